// Round 10
// baseline (263.695 us; speedup 1.0000x reference)
//
#include <hip/hip_runtime.h>
#include <hip/hip_bf16.h>
#include <math.h>

typedef __hip_bfloat16 bf16;
static __device__ __forceinline__ float b2f(bf16 v) { return __bfloat162float(v); }

typedef __bf16 bfx8 __attribute__((ext_vector_type(8)));
typedef float  fx4  __attribute__((ext_vector_type(4)));

constexpr int NN = 200000;   // nodes
constexpr int NE = 600000;   // edges
constexpr int NG = 512;      // graphs
constexpr int KB = 16;       // bucket capacity (Poisson(3): P(deg>16) tiny; overflow scan inline)
constexpr int OVFCAP = 8192;

// ---------------- bucket edges by dst (also produces in-degree in cnt) ----------------
__global__ void k_bucket(const int* __restrict__ ei, int* __restrict__ cnt,
                         int* __restrict__ bkt, int* __restrict__ ovf, int* __restrict__ novf) {
    int e = blockIdx.x * blockDim.x + threadIdx.x;
    if (e >= NE) return;
    int s = ei[e], d = ei[NE + e];
    int slot = atomicAdd(&cnt[d], 1);
    if (slot < KB) bkt[d * KB + slot] = s;
    else { int o = atomicAdd(novf, 1); if (o < OVFCAP) ovf[o] = e; }
}

// counts[g] via binary search on the SORTED batch array (no atomics)
__global__ void k_countsb(const int* __restrict__ batch, float* __restrict__ counts) {
    int g = blockIdx.x * blockDim.x + threadIdx.x;
    if (g >= NG) return;
    int lo = 0, hi = NN;
    while (lo < hi) { int m = (lo + hi) >> 1; if (batch[m] < g) lo = m + 1; else hi = m; }
    int first = lo;
    lo = 0; hi = NN;
    while (lo < hi) { int m = (lo + hi) >> 1; if (batch[m] < g + 1) lo = m + 1; else hi = m; }
    counts[g] = (float)(lo - first);
}

__global__ void k_dis(const int* __restrict__ cnt, float* __restrict__ dis) {
    int n = blockIdx.x * blockDim.x + threadIdx.x;
    if (n < NN) dis[n] = rsqrtf((float)cnt[n] + 1.0f);   // +1 self-loop
}

// ---------------- W2 (fp32 [64][128]) -> bf16 TRANSPOSED [128 cols][64 k] ----------------
__global__ void k_w2b(const float* __restrict__ W2, short* __restrict__ w2t) {
    int t = blockIdx.x * blockDim.x + threadIdx.x;
    if (t >= 64 * 128) return;
    int k = t >> 7, c = t & 127;
    bf16 v = __float2bfloat16(W2[t]);
    w2t[c * 64 + k] = *(const short*)&v;
}

// ---------------- fused GCN layer 1, wave per node:
// lanes 0..deg-1 gather x[s]*dis[s] in parallel from bkt, shfl reduce, then all
// 64 lanes compute their channel of h1 = relu(((sum + x[d]*dis[d])*dis[d])@W1+b1).
__global__ __launch_bounds__(256) void k_h1g(const int* __restrict__ cnt,
                      const int* __restrict__ bkt, const float* __restrict__ dis,
                      const float* __restrict__ x, const float* __restrict__ W1,
                      const float* __restrict__ b1,
                      const int* __restrict__ novf, const int* __restrict__ ovf,
                      const int* __restrict__ ei, bf16* __restrict__ h1) {
    int d = (blockIdx.x * 256 + threadIdx.x) >> 6;
    if (d >= NN) return;
    int lane = threadIdx.x & 63;
    int deg = cnt[d];
    int degc = deg < KB ? deg : KB;

    float p0 = 0.0f, p1 = 0.0f;
    if (lane < degc) {
        int s = bkt[d * KB + lane];
        float ws = dis[s];
        float2 xs = ((const float2*)x)[s];
        p0 = xs.x * ws; p1 = xs.y * ws;
    }
    if (deg > KB) {                       // rare overflow: scan tiny ovf list
        int nov = *novf; if (nov > OVFCAP) nov = OVFCAP;
        for (int o = lane; o < nov; o += 64) {
            int e = ovf[o];
            if (ei[NE + e] == d) {
                int s = ei[e];
                float ws = dis[s];
                float2 xs = ((const float2*)x)[s];
                p0 += xs.x * ws; p1 += xs.y * ws;
            }
        }
    }
#pragma unroll
    for (int m = 1; m < 64; m <<= 1) {
        p0 += __shfl_xor(p0, m, 64);
        p1 += __shfl_xor(p1, m, 64);
    }

    float wd = dis[d];
    float2 xd = ((const float2*)x)[d];
    float a0 = (p0 + xd.x * wd) * wd;
    float a1 = (p1 + xd.y * wd) * wd;
    float v = fmaxf(a0 * W1[lane] + a1 * W1[64 + lane] + b1[lane], 0.0f);
    h1[(size_t)d * 64 + lane] = __float2bfloat16(v);
}

// ---------------- GATHER aggregation, wave per dst node, ILP-4; bf16 output ----------------
// aggb[d][k] = bf16( (sum_s h1[s][k]*dis[s] + h1[d][k]*dis[d]) * dis[d] )
__global__ __launch_bounds__(256) void k_agg(const int* __restrict__ cnt,
                        const int* __restrict__ bkt, const float* __restrict__ dis,
                        const bf16* __restrict__ h1,
                        const int* __restrict__ novf, const int* __restrict__ ovf,
                        const int* __restrict__ ei, short* __restrict__ aggb) {
    int d = (blockIdx.x * 256 + threadIdx.x) >> 6;
    if (d >= NN) return;
    int lane = threadIdx.x & 63;
    int deg = cnt[d];
    int degc = deg < KB ? deg : KB;
    float dd = dis[d];
    float acc = b2f(h1[(size_t)d * 64 + lane]) * dd;      // self-loop term
    int base = d * KB;
    for (int i = 0; i < degc; i += 4) {
        int c = degc - 1;
        int i1 = i + 1 < c ? i + 1 : c;
        int i2 = i + 2 < c ? i + 2 : c;
        int i3 = i + 3 < c ? i + 3 : c;
        int s0 = bkt[base + i], s1 = bkt[base + i1];
        int s2 = bkt[base + i2], s3 = bkt[base + i3];
        float v0 = b2f(h1[(size_t)s0 * 64 + lane]) * dis[s0];
        float v1 = b2f(h1[(size_t)s1 * 64 + lane]) * dis[s1];
        float v2 = b2f(h1[(size_t)s2 * 64 + lane]) * dis[s2];
        float v3 = b2f(h1[(size_t)s3 * 64 + lane]) * dis[s3];
        acc += v0;
        if (i + 1 < degc) acc += v1;
        if (i + 2 < degc) acc += v2;
        if (i + 3 < degc) acc += v3;
    }
    if (deg > KB) {                       // rare overflow: all lanes scan ovf list
        int nov = *novf; if (nov > OVFCAP) nov = OVFCAP;
        for (int o = 0; o < nov; o++) {
            int e = ovf[o];
            if (ei[NE + e] == d) {
                int s = ei[e];
                acc += b2f(h1[(size_t)s * 64 + lane]) * dis[s];
            }
        }
    }
    bf16 r = __float2bfloat16(acc * dd);
    aggb[(size_t)d * 64 + lane] = *(const short*)&r;
}

// ---------------- MFMA: h2 = relu(aggb @ W2 + b2), segment-merged pool ----------------
// Wave per 16-node tile. A-frags from global (2KB contiguous tile);
// B-frags from bf16-transposed W2 (L1/L2-hot). Layouts (m89-verified):
// A[row=lane&15][k=(lane>>4)*8+i]; B[k][col=lane&15]; D[row=(lane>>4)*4+reg][col=lane&15].
__global__ __launch_bounds__(256) void k_l2mm(const short* __restrict__ aggb,
                        const short* __restrict__ w2t, const float* __restrict__ b2,
                        const int* __restrict__ batch, float* __restrict__ pooled) {
    int lane = threadIdx.x & 63;
    int tile = (blockIdx.x * 256 + threadIdx.x) >> 6;   // 16-node tile id
    int n0 = tile * 16;
    if (n0 >= NN) return;
    int lr = lane & 15, lq = lane >> 4;

    const short* arow = aggb + (size_t)(n0 + lr) * 64 + lq * 8;
    bfx8 a0 = *(const bfx8*)(arow);
    bfx8 a1 = *(const bfx8*)(arow + 32);

    int r0 = n0 + lq * 4;                 // my 4 output rows
    int g0 = batch[r0 + 0], g1 = batch[r0 + 1];
    int g2 = batch[r0 + 2], g3 = batch[r0 + 3];

    for (int t = 0; t < 8; t++) {
        int c = t * 16 + lr;
        const short* bcol = w2t + c * 64 + lq * 8;
        bfx8 b0 = *(const bfx8*)(bcol);
        bfx8 b1 = *(const bfx8*)(bcol + 32);
        fx4 acc = {0.0f, 0.0f, 0.0f, 0.0f};
        acc = __builtin_amdgcn_mfma_f32_16x16x32_bf16(a0, b0, acc, 0, 0, 0);
        acc = __builtin_amdgcn_mfma_f32_16x16x32_bf16(a1, b1, acc, 0, 0, 0);
        float bias = b2[c];
        float v0 = fmaxf(acc[0] + bias, 0.0f);
        float v1 = fmaxf(acc[1] + bias, 0.0f);
        float v2 = fmaxf(acc[2] + bias, 0.0f);
        float v3 = fmaxf(acc[3] + bias, 0.0f);
        // merge consecutive rows with equal graph id (batch sorted) -> ~1 atomic/lane
        float s = v0; int cg = g0;
        if (g1 == cg) s += v1; else { atomicAdd(&pooled[cg * 128 + c], s); s = v1; cg = g1; }
        if (g2 == cg) s += v2; else { atomicAdd(&pooled[cg * 128 + c], s); s = v2; cg = g2; }
        if (g3 == cg) s += v3; else { atomicAdd(&pooled[cg * 128 + c], s); s = v3; cg = g3; }
        atomicAdd(&pooled[cg * 128 + c], s);
    }
}

// ---------------- fused head: feat MLP + fusion MLP + sigmoid, block per graph ----------------
__global__ void k_head(const float* __restrict__ feat,
                       const float* __restrict__ fW1, const float* __restrict__ fb1,
                       const float* __restrict__ fg1, const float* __restrict__ fbe1,
                       const float* __restrict__ frm1, const float* __restrict__ frv1,
                       const float* __restrict__ fW2, const float* __restrict__ fb2,
                       const float* __restrict__ uW1, const float* __restrict__ ub1,
                       const float* __restrict__ ug1, const float* __restrict__ ube1,
                       const float* __restrict__ urm1, const float* __restrict__ urv1,
                       const float* __restrict__ uW2, const float* __restrict__ ub2,
                       const float* __restrict__ ug2, const float* __restrict__ ube2,
                       const float* __restrict__ urm2, const float* __restrict__ urv2,
                       const float* __restrict__ uW3, const float* __restrict__ ub3,
                       const float* __restrict__ pooled, const float* __restrict__ counts,
                       float* __restrict__ out) {
    int g = blockIdx.x;
    int tid = threadIdx.x;
    __shared__ float t1[256], c[256], d1[192], d2[128];

    float f[8];
#pragma unroll
    for (int i = 0; i < 8; i++) f[i] = feat[g * 8 + i];

    {
        int j = tid;
        float acc = fb1[j];
#pragma unroll
        for (int i = 0; i < 8; i++) acc += f[i] * fW1[i * 256 + j];
        acc = (acc - frm1[j]) * rsqrtf(frv1[j] + 1e-5f) * fg1[j] + fbe1[j];
        t1[j] = fmaxf(acc, 0.0f);
    }
    __syncthreads();

    if (tid < 128) {
        float acc = fb2[tid];
        for (int j = 0; j < 256; j++) acc += t1[j] * fW2[j * 128 + tid];
        c[128 + tid] = acc;
    } else {
        int k = tid - 128;
        float cnt = fmaxf(counts[g], 1.0f);
        c[k] = pooled[g * 128 + k] / cnt;
    }
    __syncthreads();

    if (tid < 192) {
        float acc = ub1[tid];
        for (int i = 0; i < 256; i++) acc += c[i] * uW1[i * 192 + tid];
        acc = (acc - urm1[tid]) * rsqrtf(urv1[tid] + 1e-5f) * ug1[tid] + ube1[tid];
        d1[tid] = fmaxf(acc, 0.0f);
    }
    __syncthreads();

    if (tid < 128) {
        float acc = ub2[tid];
        for (int i = 0; i < 192; i++) acc += d1[i] * uW2[i * 128 + tid];
        acc = (acc - urm2[tid]) * rsqrtf(urv2[tid] + 1e-5f) * ug2[tid] + ube2[tid];
        d2[tid] = fmaxf(acc, 0.0f);
    }
    __syncthreads();

    if (tid == 0) {
        float s = ub3[0];
        for (int i = 0; i < 128; i++) s += d2[i] * uW3[i];
        out[g] = 1.0f / (1.0f + expf(-s));
    }
}

extern "C" void kernel_launch(void* const* d_in, const int* in_sizes, int n_in,
                              void* d_out, int out_size, void* d_ws, size_t ws_size,
                              hipStream_t stream) {
    const float* x    = (const float*)d_in[0];
    const float* feat = (const float*)d_in[1];
    const float* W1   = (const float*)d_in[2];
    const float* b1   = (const float*)d_in[3];
    const float* W2   = (const float*)d_in[4];
    const float* b2   = (const float*)d_in[5];
    const float* fW1  = (const float*)d_in[6];
    const float* fb1  = (const float*)d_in[7];
    const float* fg1  = (const float*)d_in[8];
    const float* fbe1 = (const float*)d_in[9];
    const float* frm1 = (const float*)d_in[10];
    const float* frv1 = (const float*)d_in[11];
    const float* fW2  = (const float*)d_in[12];
    const float* fb2  = (const float*)d_in[13];
    const float* uW1  = (const float*)d_in[14];
    const float* ub1  = (const float*)d_in[15];
    const float* ug1  = (const float*)d_in[16];
    const float* ube1 = (const float*)d_in[17];
    const float* urm1 = (const float*)d_in[18];
    const float* urv1 = (const float*)d_in[19];
    const float* uW2  = (const float*)d_in[20];
    const float* ub2  = (const float*)d_in[21];
    const float* ug2  = (const float*)d_in[22];
    const float* ube2 = (const float*)d_in[23];
    const float* urm2 = (const float*)d_in[24];
    const float* urv2 = (const float*)d_in[25];
    const float* uW3  = (const float*)d_in[26];
    const float* ub3  = (const float*)d_in[27];
    const int* ei    = (const int*)d_in[28];   // [2, E]
    const int* batch = (const int*)d_in[29];   // [N]
    float* out = (float*)d_out;

    // workspace layout — total ~67 MB
    char* p = (char*)d_ws;
    float* dis    = (float*)p; p += (size_t)NN * 4;
    short* aggb   = (short*)p; p += (size_t)NN * 64 * 2;       // bf16 gather output
    bf16*  h1     = (bf16*)p;  p += (size_t)NN * 64 * 2;
    float* counts = (float*)p; p += (size_t)NG * 4;
    float* pooled = (float*)p; p += (size_t)NG * 128 * 4;
    int*   cnt    = (int*)p;   p += (size_t)NN * 4;            // in-degree / bucket cursor
    int*   bkt    = (int*)p;   p += (size_t)NN * KB * 4;       // src ids bucketed by dst
    int*   novf   = (int*)p;   p += 4;
    int*   ovf    = (int*)p;   p += (size_t)OVFCAP * 4;
    short* w2t    = (short*)p; p += (size_t)64 * 128 * 2;      // bf16 W2, transposed [col][k]

    hipMemsetAsync(cnt,    0, (size_t)NN * 4, stream);
    hipMemsetAsync(novf,   0, 4, stream);
    hipMemsetAsync(pooled, 0, (size_t)NG * 128 * 4, stream);

    k_bucket<<<(NE + 255) / 256, 256, 0, stream>>>(ei, cnt, bkt, ovf, novf);
    k_countsb<<<(NG + 255) / 256, 256, 0, stream>>>(batch, counts);
    k_dis<<<(NN + 255) / 256, 256, 0, stream>>>(cnt, dis);
    k_w2b<<<32, 256, 0, stream>>>(W2, w2t);

    // GCN layer 1: fused parallel-gather + W1 + bias + relu (wave per node)
    k_h1g<<<(NN * 64 + 255) / 256, 256, 0, stream>>>(cnt, bkt, dis, x, W1, b1,
                                                     novf, ovf, ei, h1);

    // GCN layer 2: ILP-4 gather (bf16 out), then MFMA matmul + segment pool
    k_agg<<<(NN * 64 + 255) / 256, 256, 0, stream>>>(cnt, bkt, dis, h1, novf, ovf, ei, aggb);
    k_l2mm<<<(NN / 16 * 64) / 256, 256, 0, stream>>>(aggb, w2t, b2, batch, pooled);

    // fused MLP head
    k_head<<<NG, 256, 0, stream>>>(feat, fW1, fb1, fg1, fbe1, frm1, frv1, fW2, fb2,
                                   uW1, ub1, ug1, ube1, urm1, urv1,
                                   uW2, ub2, ug2, ube2, urm2, urv2, uW3, ub3,
                                   pooled, counts, out);
}

// Round 11
// 199.568 us; speedup vs baseline: 1.3213x; 1.3213x over previous
//
#include <hip/hip_runtime.h>
#include <hip/hip_bf16.h>
#include <math.h>

typedef __hip_bfloat16 bf16;
static __device__ __forceinline__ float b2f(bf16 v) { return __bfloat162float(v); }

typedef __bf16 bfx8 __attribute__((ext_vector_type(8)));
typedef float  fx4  __attribute__((ext_vector_type(4)));

constexpr int NN = 200000;   // nodes
constexpr int NE = 600000;   // edges
constexpr int NG = 512;      // graphs
constexpr int KB = 16;       // bucket capacity (Poisson(3): P(deg>16) tiny; overflow scan inline)
constexpr int OVFCAP = 8192;

// ---------------- bucket edges by dst (also produces in-degree in cnt) ----------------
__global__ void k_bucket(const int* __restrict__ ei, int* __restrict__ cnt,
                         int* __restrict__ bkt, int* __restrict__ ovf, int* __restrict__ novf) {
    int e = blockIdx.x * blockDim.x + threadIdx.x;
    if (e >= NE) return;
    int s = ei[e], d = ei[NE + e];
    int slot = atomicAdd(&cnt[d], 1);
    if (slot < KB) bkt[d * KB + slot] = s;
    else { int o = atomicAdd(novf, 1); if (o < OVFCAP) ovf[o] = e; }
}

// counts[g] via binary search on the SORTED batch array (no atomics)
__global__ void k_countsb(const int* __restrict__ batch, float* __restrict__ counts) {
    int g = blockIdx.x * blockDim.x + threadIdx.x;
    if (g >= NG) return;
    int lo = 0, hi = NN;
    while (lo < hi) { int m = (lo + hi) >> 1; if (batch[m] < g) lo = m + 1; else hi = m; }
    int first = lo;
    lo = 0; hi = NN;
    while (lo < hi) { int m = (lo + hi) >> 1; if (batch[m] < g + 1) lo = m + 1; else hi = m; }
    counts[g] = (float)(lo - first);
}

__global__ void k_dis(const int* __restrict__ cnt, float* __restrict__ dis) {
    int n = blockIdx.x * blockDim.x + threadIdx.x;
    if (n < NN) dis[n] = rsqrtf((float)cnt[n] + 1.0f);   // +1 self-loop
}

// ---------------- W2 (fp32 [64][128]) -> bf16 TRANSPOSED [128 cols][64 k] ----------------
__global__ void k_w2b(const float* __restrict__ W2, short* __restrict__ w2t) {
    int t = blockIdx.x * blockDim.x + threadIdx.x;
    if (t >= 64 * 128) return;
    int k = t >> 7, c = t & 127;
    bf16 v = __float2bfloat16(W2[t]);
    w2t[c * 64 + k] = *(const short*)&v;
}

// ---------------- fused GCN layer 1, wave per node:
// lanes 0..deg-1 gather x[s]*dis[s] in parallel from bkt, shfl reduce, then all
// 64 lanes compute their channel of h1 = relu(((sum + x[d]*dis[d])*dis[d])@W1+b1).
__global__ __launch_bounds__(256) void k_h1g(const int* __restrict__ cnt,
                      const int* __restrict__ bkt, const float* __restrict__ dis,
                      const float* __restrict__ x, const float* __restrict__ W1,
                      const float* __restrict__ b1,
                      const int* __restrict__ novf, const int* __restrict__ ovf,
                      const int* __restrict__ ei, bf16* __restrict__ h1) {
    int d = (blockIdx.x * 256 + threadIdx.x) >> 6;
    if (d >= NN) return;
    int lane = threadIdx.x & 63;
    int deg = cnt[d];
    int degc = deg < KB ? deg : KB;

    float p0 = 0.0f, p1 = 0.0f;
    if (lane < degc) {
        int s = bkt[d * KB + lane];
        float ws = dis[s];
        float2 xs = ((const float2*)x)[s];
        p0 = xs.x * ws; p1 = xs.y * ws;
    }
    if (deg > KB) {                       // rare overflow: scan tiny ovf list
        int nov = *novf; if (nov > OVFCAP) nov = OVFCAP;
        for (int o = lane; o < nov; o += 64) {
            int e = ovf[o];
            if (ei[NE + e] == d) {
                int s = ei[e];
                float ws = dis[s];
                float2 xs = ((const float2*)x)[s];
                p0 += xs.x * ws; p1 += xs.y * ws;
            }
        }
    }
#pragma unroll
    for (int m = 1; m < 64; m <<= 1) {
        p0 += __shfl_xor(p0, m, 64);
        p1 += __shfl_xor(p1, m, 64);
    }

    float wd = dis[d];
    float2 xd = ((const float2*)x)[d];
    float a0 = (p0 + xd.x * wd) * wd;
    float a1 = (p1 + xd.y * wd) * wd;
    float v = fmaxf(a0 * W1[lane] + a1 * W1[64 + lane] + b1[lane], 0.0f);
    h1[(size_t)d * 64 + lane] = __float2bfloat16(v);
}

// ---------------- GATHER aggregation, wave per dst node; int4 bucket load + ILP-4 ----------------
// aggb[d][k] = bf16( (sum_s h1[s][k]*dis[s] + h1[d][k]*dis[d]) * dis[d] )
__global__ __launch_bounds__(256) void k_agg(const int* __restrict__ cnt,
                        const int* __restrict__ bkt, const float* __restrict__ dis,
                        const bf16* __restrict__ h1,
                        const int* __restrict__ novf, const int* __restrict__ ovf,
                        const int* __restrict__ ei, short* __restrict__ aggb) {
    int d = (blockIdx.x * 256 + threadIdx.x) >> 6;
    if (d >= NN) return;
    int lane = threadIdx.x & 63;
    int deg = cnt[d];
    int degc = deg < KB ? deg : KB;
    float dd = dis[d];
    float acc = b2f(h1[(size_t)d * 64 + lane]) * dd;      // self-loop term
    int base = d * KB;
    for (int i = 0; i < degc; i += 4) {
        int4 sv = *(const int4*)&bkt[base + i];           // 16B-aligned (KB=16)
        int s0 = sv.x;
        int s1 = (i + 1 < degc) ? sv.y : s0;              // clamp BEFORE use as index
        int s2 = (i + 2 < degc) ? sv.z : s0;
        int s3 = (i + 3 < degc) ? sv.w : s0;
        float v0 = b2f(h1[(size_t)s0 * 64 + lane]) * dis[s0];
        float v1 = b2f(h1[(size_t)s1 * 64 + lane]) * dis[s1];
        float v2 = b2f(h1[(size_t)s2 * 64 + lane]) * dis[s2];
        float v3 = b2f(h1[(size_t)s3 * 64 + lane]) * dis[s3];
        acc += v0;
        if (i + 1 < degc) acc += v1;
        if (i + 2 < degc) acc += v2;
        if (i + 3 < degc) acc += v3;
    }
    if (deg > KB) {                       // rare overflow: all lanes scan ovf list
        int nov = *novf; if (nov > OVFCAP) nov = OVFCAP;
        for (int o = 0; o < nov; o++) {
            int e = ovf[o];
            if (ei[NE + e] == d) {
                int s = ei[e];
                acc += b2f(h1[(size_t)s * 64 + lane]) * dis[s];
            }
        }
    }
    bf16 r = __float2bfloat16(acc * dd);
    aggb[(size_t)d * 64 + lane] = *(const short*)&r;
}

// ---------------- MFMA: h2 = relu(aggb @ W2 + b2), cross-lane-reduced pool ----------------
// Wave per 16-node tile. Round-10 lesson: per-lane atomics = 44MB RMW = bound.
// Fix: tiles are ~96% single-graph (batch sorted, ~390 nodes/graph) -> shfl_xor
// over the 4 lq row-groups, one atomic per col from lq==0 lanes: 128 atomics/wave.
__global__ __launch_bounds__(256) void k_l2mm(const short* __restrict__ aggb,
                        const short* __restrict__ w2t, const float* __restrict__ b2,
                        const int* __restrict__ batch, float* __restrict__ pooled) {
    int lane = threadIdx.x & 63;
    int tile = (blockIdx.x * 256 + threadIdx.x) >> 6;   // 16-node tile id
    int n0 = tile * 16;
    if (n0 >= NN) return;
    int lr = lane & 15, lq = lane >> 4;

    const short* arow = aggb + (size_t)(n0 + lr) * 64 + lq * 8;
    bfx8 a0 = *(const bfx8*)(arow);
    bfx8 a1 = *(const bfx8*)(arow + 32);

    int r0 = n0 + lq * 4;                 // my 4 output rows
    int g0 = batch[r0 + 0], g1 = batch[r0 + 1];
    int g2 = batch[r0 + 2], g3 = batch[r0 + 3];
    bool uni = (batch[n0] == batch[n0 + 15]);   // wave-uniform

    for (int t = 0; t < 8; t++) {
        int c = t * 16 + lr;
        const short* bcol = w2t + c * 64 + lq * 8;
        bfx8 b0 = *(const bfx8*)(bcol);
        bfx8 b1 = *(const bfx8*)(bcol + 32);
        fx4 acc = {0.0f, 0.0f, 0.0f, 0.0f};
        acc = __builtin_amdgcn_mfma_f32_16x16x32_bf16(a0, b0, acc, 0, 0, 0);
        acc = __builtin_amdgcn_mfma_f32_16x16x32_bf16(a1, b1, acc, 0, 0, 0);
        float bias = b2[c];
        float v0 = fmaxf(acc[0] + bias, 0.0f);
        float v1 = fmaxf(acc[1] + bias, 0.0f);
        float v2 = fmaxf(acc[2] + bias, 0.0f);
        float v3 = fmaxf(acc[3] + bias, 0.0f);
        if (uni) {
            float s = (v0 + v1) + (v2 + v3);
            s += __shfl_xor(s, 16, 64);
            s += __shfl_xor(s, 32, 64);
            if (lq == 0) atomicAdd(&pooled[g0 * 128 + c], s);
        } else {
            float s = v0; int cg = g0;
            if (g1 == cg) s += v1; else { atomicAdd(&pooled[cg * 128 + c], s); s = v1; cg = g1; }
            if (g2 == cg) s += v2; else { atomicAdd(&pooled[cg * 128 + c], s); s = v2; cg = g2; }
            if (g3 == cg) s += v3; else { atomicAdd(&pooled[cg * 128 + c], s); s = v3; cg = g3; }
            atomicAdd(&pooled[cg * 128 + c], s);
        }
    }
}

// ---------------- fused head: feat MLP + fusion MLP + sigmoid, block per graph ----------------
__global__ void k_head(const float* __restrict__ feat,
                       const float* __restrict__ fW1, const float* __restrict__ fb1,
                       const float* __restrict__ fg1, const float* __restrict__ fbe1,
                       const float* __restrict__ frm1, const float* __restrict__ frv1,
                       const float* __restrict__ fW2, const float* __restrict__ fb2,
                       const float* __restrict__ uW1, const float* __restrict__ ub1,
                       const float* __restrict__ ug1, const float* __restrict__ ube1,
                       const float* __restrict__ urm1, const float* __restrict__ urv1,
                       const float* __restrict__ uW2, const float* __restrict__ ub2,
                       const float* __restrict__ ug2, const float* __restrict__ ube2,
                       const float* __restrict__ urm2, const float* __restrict__ urv2,
                       const float* __restrict__ uW3, const float* __restrict__ ub3,
                       const float* __restrict__ pooled, const float* __restrict__ counts,
                       float* __restrict__ out) {
    int g = blockIdx.x;
    int tid = threadIdx.x;
    __shared__ float t1[256], c[256], d1[192], d2[128];

    float f[8];
#pragma unroll
    for (int i = 0; i < 8; i++) f[i] = feat[g * 8 + i];

    {
        int j = tid;
        float acc = fb1[j];
#pragma unroll
        for (int i = 0; i < 8; i++) acc += f[i] * fW1[i * 256 + j];
        acc = (acc - frm1[j]) * rsqrtf(frv1[j] + 1e-5f) * fg1[j] + fbe1[j];
        t1[j] = fmaxf(acc, 0.0f);
    }
    __syncthreads();

    if (tid < 128) {
        float acc = fb2[tid];
        for (int j = 0; j < 256; j++) acc += t1[j] * fW2[j * 128 + tid];
        c[128 + tid] = acc;
    } else {
        int k = tid - 128;
        float cnt = fmaxf(counts[g], 1.0f);
        c[k] = pooled[g * 128 + k] / cnt;
    }
    __syncthreads();

    if (tid < 192) {
        float acc = ub1[tid];
        for (int i = 0; i < 256; i++) acc += c[i] * uW1[i * 192 + tid];
        acc = (acc - urm1[tid]) * rsqrtf(urv1[tid] + 1e-5f) * ug1[tid] + ube1[tid];
        d1[tid] = fmaxf(acc, 0.0f);
    }
    __syncthreads();

    if (tid < 128) {
        float acc = ub2[tid];
        for (int i = 0; i < 192; i++) acc += d1[i] * uW2[i * 128 + tid];
        acc = (acc - urm2[tid]) * rsqrtf(urv2[tid] + 1e-5f) * ug2[tid] + ube2[tid];
        d2[tid] = fmaxf(acc, 0.0f);
    }
    __syncthreads();

    if (tid == 0) {
        float s = ub3[0];
        for (int i = 0; i < 128; i++) s += d2[i] * uW3[i];
        out[g] = 1.0f / (1.0f + expf(-s));
    }
}

extern "C" void kernel_launch(void* const* d_in, const int* in_sizes, int n_in,
                              void* d_out, int out_size, void* d_ws, size_t ws_size,
                              hipStream_t stream) {
    const float* x    = (const float*)d_in[0];
    const float* feat = (const float*)d_in[1];
    const float* W1   = (const float*)d_in[2];
    const float* b1   = (const float*)d_in[3];
    const float* W2   = (const float*)d_in[4];
    const float* b2   = (const float*)d_in[5];
    const float* fW1  = (const float*)d_in[6];
    const float* fb1  = (const float*)d_in[7];
    const float* fg1  = (const float*)d_in[8];
    const float* fbe1 = (const float*)d_in[9];
    const float* frm1 = (const float*)d_in[10];
    const float* frv1 = (const float*)d_in[11];
    const float* fW2  = (const float*)d_in[12];
    const float* fb2  = (const float*)d_in[13];
    const float* uW1  = (const float*)d_in[14];
    const float* ub1  = (const float*)d_in[15];
    const float* ug1  = (const float*)d_in[16];
    const float* ube1 = (const float*)d_in[17];
    const float* urm1 = (const float*)d_in[18];
    const float* urv1 = (const float*)d_in[19];
    const float* uW2  = (const float*)d_in[20];
    const float* ub2  = (const float*)d_in[21];
    const float* ug2  = (const float*)d_in[22];
    const float* ube2 = (const float*)d_in[23];
    const float* urm2 = (const float*)d_in[24];
    const float* urv2 = (const float*)d_in[25];
    const float* uW3  = (const float*)d_in[26];
    const float* ub3  = (const float*)d_in[27];
    const int* ei    = (const int*)d_in[28];   // [2, E]
    const int* batch = (const int*)d_in[29];   // [N]
    float* out = (float*)d_out;

    // workspace layout — total ~67 MB
    char* p = (char*)d_ws;
    float* dis    = (float*)p; p += (size_t)NN * 4;
    short* aggb   = (short*)p; p += (size_t)NN * 64 * 2;       // bf16 gather output
    bf16*  h1     = (bf16*)p;  p += (size_t)NN * 64 * 2;
    float* counts = (float*)p; p += (size_t)NG * 4;
    float* pooled = (float*)p; p += (size_t)NG * 128 * 4;
    int*   cnt    = (int*)p;   p += (size_t)NN * 4;            // in-degree / bucket cursor
    int*   bkt    = (int*)p;   p += (size_t)NN * KB * 4;       // src ids bucketed by dst
    int*   novf   = (int*)p;   p += 4;
    int*   ovf    = (int*)p;   p += (size_t)OVFCAP * 4;
    short* w2t    = (short*)p; p += (size_t)64 * 128 * 2;      // bf16 W2, transposed [col][k]

    hipMemsetAsync(cnt,    0, (size_t)NN * 4, stream);
    hipMemsetAsync(novf,   0, 4, stream);
    hipMemsetAsync(pooled, 0, (size_t)NG * 128 * 4, stream);

    k_bucket<<<(NE + 255) / 256, 256, 0, stream>>>(ei, cnt, bkt, ovf, novf);
    k_countsb<<<(NG + 255) / 256, 256, 0, stream>>>(batch, counts);
    k_dis<<<(NN + 255) / 256, 256, 0, stream>>>(cnt, dis);
    k_w2b<<<32, 256, 0, stream>>>(W2, w2t);

    // GCN layer 1: fused parallel-gather + W1 + bias + relu (wave per node)
    k_h1g<<<(NN * 64 + 255) / 256, 256, 0, stream>>>(cnt, bkt, dis, x, W1, b1,
                                                     novf, ovf, ei, h1);

    // GCN layer 2: gather (bf16 out), then MFMA matmul + cross-lane pool
    k_agg<<<(NN * 64 + 255) / 256, 256, 0, stream>>>(cnt, bkt, dis, h1, novf, ovf, ei, aggb);
    k_l2mm<<<(NN / 16 * 64) / 256, 256, 0, stream>>>(aggb, w2t, b2, batch, pooled);

    // fused MLP head
    k_head<<<NG, 256, 0, stream>>>(feat, fW1, fb1, fg1, fbe1, frm1, frv1, fW2, fb2,
                                   uW1, ub1, ug1, ube1, urm1, urv1,
                                   uW2, ub2, ug2, ube2, urm2, urv2, uW3, ub3,
                                   pooled, counts, out);
}

// Round 12
// 182.436 us; speedup vs baseline: 1.4454x; 1.0939x over previous
//
#include <hip/hip_runtime.h>
#include <hip/hip_bf16.h>
#include <math.h>

typedef __hip_bfloat16 bf16;
static __device__ __forceinline__ float b2f(bf16 v) { return __bfloat162float(v); }

typedef __bf16 bfx8 __attribute__((ext_vector_type(8)));
typedef float  fx4  __attribute__((ext_vector_type(4)));

constexpr int NN = 200000;   // nodes
constexpr int NE = 600000;   // edges
constexpr int NG = 512;      // graphs
constexpr int KB = 16;       // bucket capacity (Poisson(3): P(deg>16) tiny; overflow path kept)
constexpr int OVFCAP = 8192;

static __device__ __forceinline__ int clampi(int s) {
    return ((unsigned)s < (unsigned)NN) ? s : 0;   // safe addr for speculative loads
}

// ---------------- bucket edges by dst (also produces in-degree in cnt) ----------------
__global__ void k_bucket(const int* __restrict__ ei, int* __restrict__ cnt,
                         int* __restrict__ bkt, int* __restrict__ ovf, int* __restrict__ novf) {
    int e = blockIdx.x * blockDim.x + threadIdx.x;
    if (e >= NE) return;
    int s = ei[e], d = ei[NE + e];
    int slot = atomicAdd(&cnt[d], 1);
    if (slot < KB) bkt[d * KB + slot] = s;
    else { int o = atomicAdd(novf, 1); if (o < OVFCAP) ovf[o] = e; }
}

// ---------------- misc: counts[g] by binary search  +  W2 -> bf16 transposed ----------------
__global__ void k_misc(const int* __restrict__ batch, float* __restrict__ counts,
                       const float* __restrict__ W2, short* __restrict__ w2t) {
    int t = blockIdx.x * blockDim.x + threadIdx.x;
    if (t < 64 * 128) {                  // W2 [64][128] fp32 -> w2t [128 cols][64 k] bf16
        int k = t >> 7, c = t & 127;
        bf16 v = __float2bfloat16(W2[t]);
        w2t[c * 64 + k] = *(const short*)&v;
    }
    if (t < NG) {
        int g = t;
        int lo = 0, hi = NN;
        while (lo < hi) { int m = (lo + hi) >> 1; if (batch[m] < g) lo = m + 1; else hi = m; }
        int first = lo;
        lo = 0; hi = NN;
        while (lo < hi) { int m = (lo + hi) >> 1; if (batch[m] < g + 1) lo = m + 1; else hi = m; }
        counts[g] = (float)(lo - first);
    }
}

__global__ void k_dis(const int* __restrict__ cnt, float* __restrict__ dis) {
    int n = blockIdx.x * blockDim.x + threadIdx.x;
    if (n < NN) dis[n] = rsqrtf((float)cnt[n] + 1.0f);   // +1 self-loop
}

// ---------------- fused GCN layer 1, wave per node; SPECULATIVE bkt+x loads ----------------
__global__ __launch_bounds__(256) void k_h1g(const int* __restrict__ cnt,
                      const int* __restrict__ bkt, const float* __restrict__ dis,
                      const float* __restrict__ x, const float* __restrict__ W1,
                      const float* __restrict__ b1,
                      const int* __restrict__ novf, const int* __restrict__ ovf,
                      const int* __restrict__ ei, bf16* __restrict__ h1) {
    int d = (blockIdx.x * 256 + threadIdx.x) >> 6;
    if (d >= NN) return;
    int lane = threadIdx.x & 63;

    // speculative: bkt load does not wait on cnt; x gather (x=1.6MB, L2-resident)
    int sraw = bkt[d * KB + (lane & 15)];
    int s = clampi(sraw);
    int deg = cnt[d];                        // in flight in parallel
    float ws = 0.0f; float2 xs = make_float2(0.0f, 0.0f);
    if (lane < 16) { ws = dis[s]; xs = ((const float2*)x)[s]; }
    int degc = deg < KB ? deg : KB;
    float p0 = (lane < degc) ? xs.x * ws : 0.0f;
    float p1 = (lane < degc) ? xs.y * ws : 0.0f;

    if (deg > KB) {                          // rare overflow: scan tiny ovf list
        int nov = *novf; if (nov > OVFCAP) nov = OVFCAP;
        for (int o = lane; o < nov; o += 64) {
            int e = ovf[o];
            if (ei[NE + e] == d) {
                int ss = ei[e];
                float w2 = dis[ss];
                float2 x2 = ((const float2*)x)[ss];
                p0 += x2.x * w2; p1 += x2.y * w2;
            }
        }
    }
#pragma unroll
    for (int m = 1; m < 64; m <<= 1) {
        p0 += __shfl_xor(p0, m, 64);
        p1 += __shfl_xor(p1, m, 64);
    }

    float wd = dis[d];
    float2 xd = ((const float2*)x)[d];
    float a0 = (p0 + xd.x * wd) * wd;
    float a1 = (p1 + xd.y * wd) * wd;
    float v = fmaxf(a0 * W1[lane] + a1 * W1[64 + lane] + b1[lane], 0.0f);
    h1[(size_t)d * 64 + lane] = __float2bfloat16(v);
}

// ---------------- rare-path tail (deg>4 and/or overflow) for the fused layer-2 gather ----------
static __device__ __forceinline__ float agg_tail(int d, int lane, int degc, int deg, float acc,
        const int* __restrict__ bkt, const float* __restrict__ dis, const bf16* __restrict__ h1,
        const int* __restrict__ novf, const int* __restrict__ ovf, const int* __restrict__ ei) {
    for (int i = 4; i < degc; i += 4) {
        int4 sv = *(const int4*)&bkt[d * KB + i];
        int s0 = clampi(sv.x), s1 = clampi(sv.y), s2 = clampi(sv.z), s3 = clampi(sv.w);
        float v0 = b2f(h1[(size_t)s0 * 64 + lane]) * dis[s0];
        float v1 = b2f(h1[(size_t)s1 * 64 + lane]) * dis[s1];
        float v2 = b2f(h1[(size_t)s2 * 64 + lane]) * dis[s2];
        float v3 = b2f(h1[(size_t)s3 * 64 + lane]) * dis[s3];
        acc += v0;
        if (i + 1 < degc) acc += v1;
        if (i + 2 < degc) acc += v2;
        if (i + 3 < degc) acc += v3;
    }
    if (deg > KB) {
        int nov = *novf; if (nov > OVFCAP) nov = OVFCAP;
        for (int o = 0; o < nov; o++) {
            int e = ovf[o];
            if (ei[NE + e] == d) {
                int ss = ei[e];
                acc += b2f(h1[(size_t)ss * 64 + lane]) * dis[ss];
            }
        }
    }
    return acc;
}

// ---------------- FUSED layer 2: gather(16 nodes -> LDS bf16) + MFMA + pooled epilogue ------
// block = 512 thr = 8 waves = one 16-node tile. Phase 1: wave w gathers nodes 2w,2w+1
// (speculative bkt int4 || cnt; clamped indices; predicated adds). Phase 2: wave w owns
// col-tile w: A-frags from LDS (stride 72 -> <=2-way bank alias = free), B from bf16 W2^T,
// 2x mfma_f32_16x16x32_bf16, then the proven uni/shfl-reduced pool (128 atomics/block).
__global__ __launch_bounds__(512) void k_l2(const int* __restrict__ cnt,
                        const int* __restrict__ bkt, const float* __restrict__ dis,
                        const bf16* __restrict__ h1,
                        const int* __restrict__ novf, const int* __restrict__ ovf,
                        const int* __restrict__ ei,
                        const short* __restrict__ w2t, const float* __restrict__ b2v,
                        const int* __restrict__ batch, float* __restrict__ pooled) {
    __shared__ short asub[16 * 72];          // bf16 bits, row stride 72 (pad)
    int tid = threadIdx.x;
    int lane = tid & 63;
    int wid = tid >> 6;                      // 0..7
    int n0 = blockIdx.x * 16;

    // ---- phase 1: gather two nodes, fully interleaved for MLP ----
    int dA = n0 + wid * 2, dB = dA + 1;
    int4 svA = *(const int4*)&bkt[dA * KB];  // speculative (parallel with cnt)
    int4 svB = *(const int4*)&bkt[dB * KB];
    int degA = cnt[dA], degB = cnt[dB];
    float ddA = dis[dA], ddB = dis[dB];
    float selfA = b2f(h1[(size_t)dA * 64 + lane]);
    float selfB = b2f(h1[(size_t)dB * 64 + lane]);

    int a0 = clampi(svA.x), a1 = clampi(svA.y), a2 = clampi(svA.z), a3 = clampi(svA.w);
    int e0 = clampi(svB.x), e1 = clampi(svB.y), e2 = clampi(svB.z), e3 = clampi(svB.w);
    float wA0 = dis[a0], wA1 = dis[a1], wA2 = dis[a2], wA3 = dis[a3];
    float wB0 = dis[e0], wB1 = dis[e1], wB2 = dis[e2], wB3 = dis[e3];
    float vA0 = b2f(h1[(size_t)a0 * 64 + lane]);
    float vA1 = b2f(h1[(size_t)a1 * 64 + lane]);
    float vA2 = b2f(h1[(size_t)a2 * 64 + lane]);
    float vA3 = b2f(h1[(size_t)a3 * 64 + lane]);
    float vB0 = b2f(h1[(size_t)e0 * 64 + lane]);
    float vB1 = b2f(h1[(size_t)e1 * 64 + lane]);
    float vB2 = b2f(h1[(size_t)e2 * 64 + lane]);
    float vB3 = b2f(h1[(size_t)e3 * 64 + lane]);

    int degcA = degA < KB ? degA : KB;
    int degcB = degB < KB ? degB : KB;
    float accA = selfA * ddA;
    accA += (degcA > 0) ? vA0 * wA0 : 0.0f;
    accA += (degcA > 1) ? vA1 * wA1 : 0.0f;
    accA += (degcA > 2) ? vA2 * wA2 : 0.0f;
    accA += (degcA > 3) ? vA3 * wA3 : 0.0f;
    float accB = selfB * ddB;
    accB += (degcB > 0) ? vB0 * wB0 : 0.0f;
    accB += (degcB > 1) ? vB1 * wB1 : 0.0f;
    accB += (degcB > 2) ? vB2 * wB2 : 0.0f;
    accB += (degcB > 3) ? vB3 * wB3 : 0.0f;
    if (degcA > 4 || degA > KB) accA = agg_tail(dA, lane, degcA, degA, accA, bkt, dis, h1, novf, ovf, ei);
    if (degcB > 4 || degB > KB) accB = agg_tail(dB, lane, degcB, degB, accB, bkt, dis, h1, novf, ovf, ei);

    bf16 rA = __float2bfloat16(accA * ddA);
    bf16 rB = __float2bfloat16(accB * ddB);
    asub[(wid * 2 + 0) * 72 + lane] = *(const short*)&rA;
    asub[(wid * 2 + 1) * 72 + lane] = *(const short*)&rB;
    __syncthreads();

    // ---- phase 2: col-tile wid ----
    int lr = lane & 15, lq = lane >> 4;
    bfx8 af0 = *(const bfx8*)&asub[lr * 72 + lq * 8];
    bfx8 af1 = *(const bfx8*)&asub[lr * 72 + 32 + lq * 8];
    int c = wid * 16 + lr;
    const short* bcol = w2t + c * 64 + lq * 8;
    bfx8 bf0 = *(const bfx8*)(bcol);
    bfx8 bf1 = *(const bfx8*)(bcol + 32);
    fx4 acc = {0.0f, 0.0f, 0.0f, 0.0f};
    acc = __builtin_amdgcn_mfma_f32_16x16x32_bf16(af0, bf0, acc, 0, 0, 0);
    acc = __builtin_amdgcn_mfma_f32_16x16x32_bf16(af1, bf1, acc, 0, 0, 0);

    int r0 = n0 + lq * 4;
    int g0 = batch[r0 + 0], g1 = batch[r0 + 1];
    int g2 = batch[r0 + 2], g3 = batch[r0 + 3];
    bool uni = (batch[n0] == batch[n0 + 15]);
    float bias = b2v[c];
    float v0 = fmaxf(acc[0] + bias, 0.0f);
    float v1 = fmaxf(acc[1] + bias, 0.0f);
    float v2 = fmaxf(acc[2] + bias, 0.0f);
    float v3 = fmaxf(acc[3] + bias, 0.0f);
    if (uni) {
        float s = (v0 + v1) + (v2 + v3);
        s += __shfl_xor(s, 16, 64);
        s += __shfl_xor(s, 32, 64);
        if (lq == 0) atomicAdd(&pooled[g0 * 128 + c], s);
    } else {
        float s = v0; int cg = g0;
        if (g1 == cg) s += v1; else { atomicAdd(&pooled[cg * 128 + c], s); s = v1; cg = g1; }
        if (g2 == cg) s += v2; else { atomicAdd(&pooled[cg * 128 + c], s); s = v2; cg = g2; }
        if (g3 == cg) s += v3; else { atomicAdd(&pooled[cg * 128 + c], s); s = v3; cg = g3; }
        atomicAdd(&pooled[cg * 128 + c], s);
    }
}

// ---------------- fused head: feat MLP + fusion MLP + sigmoid, block per graph ----------------
__global__ void k_head(const float* __restrict__ feat,
                       const float* __restrict__ fW1, const float* __restrict__ fb1,
                       const float* __restrict__ fg1, const float* __restrict__ fbe1,
                       const float* __restrict__ frm1, const float* __restrict__ frv1,
                       const float* __restrict__ fW2, const float* __restrict__ fb2,
                       const float* __restrict__ uW1, const float* __restrict__ ub1,
                       const float* __restrict__ ug1, const float* __restrict__ ube1,
                       const float* __restrict__ urm1, const float* __restrict__ urv1,
                       const float* __restrict__ uW2, const float* __restrict__ ub2,
                       const float* __restrict__ ug2, const float* __restrict__ ube2,
                       const float* __restrict__ urm2, const float* __restrict__ urv2,
                       const float* __restrict__ uW3, const float* __restrict__ ub3,
                       const float* __restrict__ pooled, const float* __restrict__ counts,
                       float* __restrict__ out) {
    int g = blockIdx.x;
    int tid = threadIdx.x;
    __shared__ float t1[256], c[256], d1[192], d2[128];

    float f[8];
#pragma unroll
    for (int i = 0; i < 8; i++) f[i] = feat[g * 8 + i];

    {
        int j = tid;
        float acc = fb1[j];
#pragma unroll
        for (int i = 0; i < 8; i++) acc += f[i] * fW1[i * 256 + j];
        acc = (acc - frm1[j]) * rsqrtf(frv1[j] + 1e-5f) * fg1[j] + fbe1[j];
        t1[j] = fmaxf(acc, 0.0f);
    }
    __syncthreads();

    if (tid < 128) {
        float acc = fb2[tid];
        for (int j = 0; j < 256; j++) acc += t1[j] * fW2[j * 128 + tid];
        c[128 + tid] = acc;
    } else {
        int k = tid - 128;
        float cnt = fmaxf(counts[g], 1.0f);
        c[k] = pooled[g * 128 + k] / cnt;
    }
    __syncthreads();

    if (tid < 192) {
        float acc = ub1[tid];
        for (int i = 0; i < 256; i++) acc += c[i] * uW1[i * 192 + tid];
        acc = (acc - urm1[tid]) * rsqrtf(urv1[tid] + 1e-5f) * ug1[tid] + ube1[tid];
        d1[tid] = fmaxf(acc, 0.0f);
    }
    __syncthreads();

    if (tid < 128) {
        float acc = ub2[tid];
        for (int i = 0; i < 192; i++) acc += d1[i] * uW2[i * 128 + tid];
        acc = (acc - urm2[tid]) * rsqrtf(urv2[tid] + 1e-5f) * ug2[tid] + ube2[tid];
        d2[tid] = fmaxf(acc, 0.0f);
    }
    __syncthreads();

    if (tid == 0) {
        float s = ub3[0];
        for (int i = 0; i < 128; i++) s += d2[i] * uW3[i];
        out[g] = 1.0f / (1.0f + expf(-s));
    }
}

extern "C" void kernel_launch(void* const* d_in, const int* in_sizes, int n_in,
                              void* d_out, int out_size, void* d_ws, size_t ws_size,
                              hipStream_t stream) {
    const float* x    = (const float*)d_in[0];
    const float* feat = (const float*)d_in[1];
    const float* W1   = (const float*)d_in[2];
    const float* b1   = (const float*)d_in[3];
    const float* W2   = (const float*)d_in[4];
    const float* b2   = (const float*)d_in[5];
    const float* fW1  = (const float*)d_in[6];
    const float* fb1  = (const float*)d_in[7];
    const float* fg1  = (const float*)d_in[8];
    const float* fbe1 = (const float*)d_in[9];
    const float* frm1 = (const float*)d_in[10];
    const float* frv1 = (const float*)d_in[11];
    const float* fW2  = (const float*)d_in[12];
    const float* fb2  = (const float*)d_in[13];
    const float* uW1  = (const float*)d_in[14];
    const float* ub1  = (const float*)d_in[15];
    const float* ug1  = (const float*)d_in[16];
    const float* ube1 = (const float*)d_in[17];
    const float* urm1 = (const float*)d_in[18];
    const float* urv1 = (const float*)d_in[19];
    const float* uW2  = (const float*)d_in[20];
    const float* ub2  = (const float*)d_in[21];
    const float* ug2  = (const float*)d_in[22];
    const float* ube2 = (const float*)d_in[23];
    const float* urm2 = (const float*)d_in[24];
    const float* urv2 = (const float*)d_in[25];
    const float* uW3  = (const float*)d_in[26];
    const float* ub3  = (const float*)d_in[27];
    const int* ei    = (const int*)d_in[28];   // [2, E]
    const int* batch = (const int*)d_in[29];   // [N]
    float* out = (float*)d_out;

    // workspace layout — total ~41 MB
    char* p = (char*)d_ws;
    float* dis    = (float*)p; p += (size_t)NN * 4;
    bf16*  h1     = (bf16*)p;  p += (size_t)NN * 64 * 2;
    float* counts = (float*)p; p += (size_t)NG * 4;
    float* pooled = (float*)p; p += (size_t)NG * 128 * 4;
    int*   cnt    = (int*)p;   p += (size_t)NN * 4;            // in-degree / bucket cursor
    int*   bkt    = (int*)p;   p += (size_t)NN * KB * 4;       // src ids bucketed by dst
    int*   novf   = (int*)p;   p += 4;
    int*   ovf    = (int*)p;   p += (size_t)OVFCAP * 4;
    short* w2t    = (short*)p; p += (size_t)64 * 128 * 2;      // bf16 W2, transposed [col][k]

    hipMemsetAsync(cnt,    0, (size_t)NN * 4, stream);
    hipMemsetAsync(novf,   0, 4, stream);
    hipMemsetAsync(pooled, 0, (size_t)NG * 128 * 4, stream);

    k_bucket<<<(NE + 255) / 256, 256, 0, stream>>>(ei, cnt, bkt, ovf, novf);
    k_misc<<<32, 256, 0, stream>>>(batch, counts, W2, w2t);
    k_dis<<<(NN + 255) / 256, 256, 0, stream>>>(cnt, dis);

    // GCN layer 1: fused parallel-gather + W1 + bias + relu (wave per node)
    k_h1g<<<(NN * 64 + 255) / 256, 256, 0, stream>>>(cnt, bkt, dis, x, W1, b1,
                                                     novf, ovf, ei, h1);

    // GCN layer 2: FUSED gather + MFMA + pool (block per 16-node tile)
    k_l2<<<NN / 16, 512, 0, stream>>>(cnt, bkt, dis, h1, novf, ovf, ei,
                                      w2t, b2, batch, pooled);

    // fused MLP head
    k_head<<<NG, 256, 0, stream>>>(feat, fW1, fb1, fg1, fbe1, frm1, frv1, fW2, fb2,
                                   uW1, ub1, ug1, ube1, urm1, urv1,
                                   uW2, ub2, ug2, ube2, urm2, urv2, uW3, ub3,
                                   pooled, counts, out);
}

// Round 13
// 177.389 us; speedup vs baseline: 1.4865x; 1.0284x over previous
//
#include <hip/hip_runtime.h>
#include <hip/hip_bf16.h>
#include <math.h>

typedef __hip_bfloat16 bf16;
static __device__ __forceinline__ float b2f(bf16 v) { return __bfloat162float(v); }

typedef __bf16 bfx8 __attribute__((ext_vector_type(8)));
typedef float  fx4  __attribute__((ext_vector_type(4)));

constexpr int NN = 200000;   // nodes
constexpr int NE = 600000;   // edges
constexpr int NG = 512;      // graphs
constexpr int KB = 16;       // bucket capacity (Poisson(3): P(deg>16) tiny; overflow path kept)
constexpr int OVFCAP = 8192;

static __device__ __forceinline__ int clampi(int s) {
    return ((unsigned)s < (unsigned)NN) ? s : 0;   // safe addr for speculative loads
}

// ---------------- bucket edges by dst (also produces in-degree in cnt) ----------------
__global__ void k_bucket(const int* __restrict__ ei, int* __restrict__ cnt,
                         int* __restrict__ bkt, int* __restrict__ ovf, int* __restrict__ novf) {
    int e = blockIdx.x * blockDim.x + threadIdx.x;
    if (e >= NE) return;
    int s = ei[e], d = ei[NE + e];
    int slot = atomicAdd(&cnt[d], 1);
    if (slot < KB) bkt[d * KB + slot] = s;
    else { int o = atomicAdd(novf, 1); if (o < OVFCAP) ovf[o] = e; }
}

// ---------------- misc: counts[g] by binary search  +  W2 -> bf16 transposed ----------------
__global__ void k_misc(const int* __restrict__ batch, float* __restrict__ counts,
                       const float* __restrict__ W2, short* __restrict__ w2t) {
    int t = blockIdx.x * blockDim.x + threadIdx.x;
    if (t < 64 * 128) {                  // W2 [64][128] fp32 -> w2t [128 cols][64 k] bf16
        int k = t >> 7, c = t & 127;
        bf16 v = __float2bfloat16(W2[t]);
        w2t[c * 64 + k] = *(const short*)&v;
    }
    if (t < NG) {
        int g = t;
        int lo = 0, hi = NN;
        while (lo < hi) { int m = (lo + hi) >> 1; if (batch[m] < g) lo = m + 1; else hi = m; }
        int first = lo;
        lo = 0; hi = NN;
        while (lo < hi) { int m = (lo + hi) >> 1; if (batch[m] < g + 1) lo = m + 1; else hi = m; }
        counts[g] = (float)(lo - first);
    }
}

// ---------------- dis = rsqrt(deg+1); xs = x * dis (pre-scaled gather operand) ----------------
__global__ void k_pre(const int* __restrict__ cnt, const float* __restrict__ x,
                      float* __restrict__ dis, float2* __restrict__ xs) {
    int n = blockIdx.x * blockDim.x + threadIdx.x;
    if (n >= NN) return;
    float v = rsqrtf((float)cnt[n] + 1.0f);
    dis[n] = v;
    float2 xv = ((const float2*)x)[n];
    xs[n] = make_float2(xv.x * v, xv.y * v);
}

// ---------------- fused GCN layer 1, wave per node; single xs[s] load per edge ----------------
// h1s[d] = relu( dis[d]*(sum_s xs[s] + xs[d]) @ W1 + b1 ) * dis[d]   (pre-scaled for layer 2)
__global__ __launch_bounds__(256) void k_h1g(const int* __restrict__ cnt,
                      const int* __restrict__ bkt, const float* __restrict__ dis,
                      const float2* __restrict__ xs, const float* __restrict__ W1,
                      const float* __restrict__ b1,
                      const int* __restrict__ novf, const int* __restrict__ ovf,
                      const int* __restrict__ ei, bf16* __restrict__ h1s) {
    int d = (blockIdx.x * 256 + threadIdx.x) >> 6;
    if (d >= NN) return;
    int lane = threadIdx.x & 63;

    // speculative: bkt + xs loads race ahead of cnt
    int s = clampi(bkt[d * KB + (lane & 15)]);
    int deg = cnt[d];
    float2 ps = make_float2(0.0f, 0.0f);
    if (lane < 16) ps = xs[s];
    int degc = deg < KB ? deg : KB;
    float p0 = (lane < degc) ? ps.x : 0.0f;
    float p1 = (lane < degc) ? ps.y : 0.0f;

    if (deg > KB) {                          // rare overflow: scan tiny ovf list
        int nov = *novf; if (nov > OVFCAP) nov = OVFCAP;
        for (int o = lane; o < nov; o += 64) {
            int e = ovf[o];
            if (ei[NE + e] == d) {
                float2 x2 = xs[ei[e]];
                p0 += x2.x; p1 += x2.y;
            }
        }
    }
#pragma unroll
    for (int m = 1; m < 64; m <<= 1) {
        p0 += __shfl_xor(p0, m, 64);
        p1 += __shfl_xor(p1, m, 64);
    }

    float wd = dis[d];
    float2 xd = xs[d];
    float a0 = (p0 + xd.x) * wd;
    float a1 = (p1 + xd.y) * wd;
    float v = fmaxf(a0 * W1[lane] + a1 * W1[64 + lane] + b1[lane], 0.0f);
    h1s[(size_t)d * 64 + lane] = __float2bfloat16(v * wd);
}

// ---------------- rare tail (deg>8 / overflow): h1s rows are pre-scaled, no dis loads --------
static __device__ __forceinline__ float agg_tail8(int d, int lane, int degc, int deg, float acc,
        const int* __restrict__ bkt, const bf16* __restrict__ h1s,
        const int* __restrict__ novf, const int* __restrict__ ovf, const int* __restrict__ ei) {
    for (int i = 8; i < degc; i += 4) {
        int4 sv = *(const int4*)&bkt[d * KB + i];
        int s0 = clampi(sv.x), s1 = clampi(sv.y), s2 = clampi(sv.z), s3 = clampi(sv.w);
        float v0 = b2f(h1s[(size_t)s0 * 64 + lane]);
        float v1 = b2f(h1s[(size_t)s1 * 64 + lane]);
        float v2 = b2f(h1s[(size_t)s2 * 64 + lane]);
        float v3 = b2f(h1s[(size_t)s3 * 64 + lane]);
        acc += v0;
        if (i + 1 < degc) acc += v1;
        if (i + 2 < degc) acc += v2;
        if (i + 3 < degc) acc += v3;
    }
    if (deg > KB) {
        int nov = *novf; if (nov > OVFCAP) nov = OVFCAP;
        for (int o = 0; o < nov; o++) {
            int e = ovf[o];
            if (ei[NE + e] == d) acc += b2f(h1s[(size_t)ei[e] * 64 + lane]);
        }
    }
    return acc;
}

// ---------------- FUSED layer 2: gather(16 nodes -> LDS bf16) + MFMA + pooled epilogue ------
// Round-12 lessons applied: (a) h1s pre-scaled -> ONE 128B row load per edge, no dis[s];
// (b) flat speculative path widened to 8 edges (wave-uniform branch), loop tail only for
// deg>8 (P~0.4%/node) -> barrier skew mostly gone.
__global__ __launch_bounds__(512) void k_l2(const int* __restrict__ cnt,
                        const int* __restrict__ bkt, const float* __restrict__ dis,
                        const bf16* __restrict__ h1s,
                        const int* __restrict__ novf, const int* __restrict__ ovf,
                        const int* __restrict__ ei,
                        const short* __restrict__ w2t, const float* __restrict__ b2v,
                        const int* __restrict__ batch, float* __restrict__ pooled) {
    __shared__ short asub[16 * 72];          // bf16 bits, row stride 72 (pad)
    int tid = threadIdx.x;
    int lane = tid & 63;
    int wid = tid >> 6;                      // 0..7
    int n0 = blockIdx.x * 16;

    // ---- phase 1: gather two nodes, loads for both issued up front ----
    int dA = n0 + wid * 2, dB = dA + 1;
    int4 svA = *(const int4*)&bkt[dA * KB];  // speculative (parallel with cnt)
    int4 svB = *(const int4*)&bkt[dB * KB];
    int degA = cnt[dA], degB = cnt[dB];
    float ddA = dis[dA], ddB = dis[dB];
    float accA = b2f(h1s[(size_t)dA * 64 + lane]);   // self term (pre-scaled)
    float accB = b2f(h1s[(size_t)dB * 64 + lane]);

    int a0 = clampi(svA.x), a1 = clampi(svA.y), a2 = clampi(svA.z), a3 = clampi(svA.w);
    int e0 = clampi(svB.x), e1 = clampi(svB.y), e2 = clampi(svB.z), e3 = clampi(svB.w);
    float vA0 = b2f(h1s[(size_t)a0 * 64 + lane]);
    float vA1 = b2f(h1s[(size_t)a1 * 64 + lane]);
    float vA2 = b2f(h1s[(size_t)a2 * 64 + lane]);
    float vA3 = b2f(h1s[(size_t)a3 * 64 + lane]);
    float vB0 = b2f(h1s[(size_t)e0 * 64 + lane]);
    float vB1 = b2f(h1s[(size_t)e1 * 64 + lane]);
    float vB2 = b2f(h1s[(size_t)e2 * 64 + lane]);
    float vB3 = b2f(h1s[(size_t)e3 * 64 + lane]);

    accA += (degA > 0) ? vA0 : 0.0f;
    accA += (degA > 1) ? vA1 : 0.0f;
    accA += (degA > 2) ? vA2 : 0.0f;
    accA += (degA > 3) ? vA3 : 0.0f;
    accB += (degB > 0) ? vB0 : 0.0f;
    accB += (degB > 1) ? vB1 : 0.0f;
    accB += (degB > 2) ? vB2 : 0.0f;
    accB += (degB > 3) ? vB3 : 0.0f;

    if (degA > 4) {                          // wave-uniform branch
        int4 s2 = *(const int4*)&bkt[dA * KB + 4];
        int b0 = clampi(s2.x), b1_ = clampi(s2.y), b2_ = clampi(s2.z), b3 = clampi(s2.w);
        float w0 = b2f(h1s[(size_t)b0 * 64 + lane]);
        float w1 = b2f(h1s[(size_t)b1_ * 64 + lane]);
        float w2 = b2f(h1s[(size_t)b2_ * 64 + lane]);
        float w3 = b2f(h1s[(size_t)b3 * 64 + lane]);
        accA += w0;
        accA += (degA > 5) ? w1 : 0.0f;
        accA += (degA > 6) ? w2 : 0.0f;
        accA += (degA > 7) ? w3 : 0.0f;
    }
    if (degB > 4) {
        int4 s2 = *(const int4*)&bkt[dB * KB + 4];
        int b0 = clampi(s2.x), b1_ = clampi(s2.y), b2_ = clampi(s2.z), b3 = clampi(s2.w);
        float w0 = b2f(h1s[(size_t)b0 * 64 + lane]);
        float w1 = b2f(h1s[(size_t)b1_ * 64 + lane]);
        float w2 = b2f(h1s[(size_t)b2_ * 64 + lane]);
        float w3 = b2f(h1s[(size_t)b3 * 64 + lane]);
        accB += w0;
        accB += (degB > 5) ? w1 : 0.0f;
        accB += (degB > 6) ? w2 : 0.0f;
        accB += (degB > 7) ? w3 : 0.0f;
    }
    if (degA > 8) accA = agg_tail8(dA, lane, degA < KB ? degA : KB, degA, accA, bkt, h1s, novf, ovf, ei);
    if (degB > 8) accB = agg_tail8(dB, lane, degB < KB ? degB : KB, degB, accB, bkt, h1s, novf, ovf, ei);

    bf16 rA = __float2bfloat16(accA * ddA);
    bf16 rB = __float2bfloat16(accB * ddB);
    asub[(wid * 2 + 0) * 72 + lane] = *(const short*)&rA;
    asub[(wid * 2 + 1) * 72 + lane] = *(const short*)&rB;
    __syncthreads();

    // ---- phase 2: col-tile wid ----
    int lr = lane & 15, lq = lane >> 4;
    bfx8 af0 = *(const bfx8*)&asub[lr * 72 + lq * 8];
    bfx8 af1 = *(const bfx8*)&asub[lr * 72 + 32 + lq * 8];
    int c = wid * 16 + lr;
    const short* bcol = w2t + c * 64 + lq * 8;
    bfx8 bf0 = *(const bfx8*)(bcol);
    bfx8 bf1 = *(const bfx8*)(bcol + 32);
    fx4 acc = {0.0f, 0.0f, 0.0f, 0.0f};
    acc = __builtin_amdgcn_mfma_f32_16x16x32_bf16(af0, bf0, acc, 0, 0, 0);
    acc = __builtin_amdgcn_mfma_f32_16x16x32_bf16(af1, bf1, acc, 0, 0, 0);

    int r0 = n0 + lq * 4;
    int g0 = batch[r0 + 0], g1 = batch[r0 + 1];
    int g2 = batch[r0 + 2], g3 = batch[r0 + 3];
    bool uni = (batch[n0] == batch[n0 + 15]);
    float bias = b2v[c];
    float v0 = fmaxf(acc[0] + bias, 0.0f);
    float v1 = fmaxf(acc[1] + bias, 0.0f);
    float v2 = fmaxf(acc[2] + bias, 0.0f);
    float v3 = fmaxf(acc[3] + bias, 0.0f);
    if (uni) {
        float s = (v0 + v1) + (v2 + v3);
        s += __shfl_xor(s, 16, 64);
        s += __shfl_xor(s, 32, 64);
        if (lq == 0) atomicAdd(&pooled[g0 * 128 + c], s);
    } else {
        float s = v0; int cg = g0;
        if (g1 == cg) s += v1; else { atomicAdd(&pooled[cg * 128 + c], s); s = v1; cg = g1; }
        if (g2 == cg) s += v2; else { atomicAdd(&pooled[cg * 128 + c], s); s = v2; cg = g2; }
        if (g3 == cg) s += v3; else { atomicAdd(&pooled[cg * 128 + c], s); s = v3; cg = g3; }
        atomicAdd(&pooled[cg * 128 + c], s);
    }
}

// ---------------- fused head: feat MLP + fusion MLP + sigmoid, block per graph ----------------
__global__ void k_head(const float* __restrict__ feat,
                       const float* __restrict__ fW1, const float* __restrict__ fb1,
                       const float* __restrict__ fg1, const float* __restrict__ fbe1,
                       const float* __restrict__ frm1, const float* __restrict__ frv1,
                       const float* __restrict__ fW2, const float* __restrict__ fb2,
                       const float* __restrict__ uW1, const float* __restrict__ ub1,
                       const float* __restrict__ ug1, const float* __restrict__ ube1,
                       const float* __restrict__ urm1, const float* __restrict__ urv1,
                       const float* __restrict__ uW2, const float* __restrict__ ub2,
                       const float* __restrict__ ug2, const float* __restrict__ ube2,
                       const float* __restrict__ urm2, const float* __restrict__ urv2,
                       const float* __restrict__ uW3, const float* __restrict__ ub3,
                       const float* __restrict__ pooled, const float* __restrict__ counts,
                       float* __restrict__ out) {
    int g = blockIdx.x;
    int tid = threadIdx.x;
    __shared__ float t1[256], c[256], d1[192], d2[128];

    float f[8];
#pragma unroll
    for (int i = 0; i < 8; i++) f[i] = feat[g * 8 + i];

    {
        int j = tid;
        float acc = fb1[j];
#pragma unroll
        for (int i = 0; i < 8; i++) acc += f[i] * fW1[i * 256 + j];
        acc = (acc - frm1[j]) * rsqrtf(frv1[j] + 1e-5f) * fg1[j] + fbe1[j];
        t1[j] = fmaxf(acc, 0.0f);
    }
    __syncthreads();

    if (tid < 128) {
        float acc = fb2[tid];
        for (int j = 0; j < 256; j++) acc += t1[j] * fW2[j * 128 + tid];
        c[128 + tid] = acc;
    } else {
        int k = tid - 128;
        float cnt = fmaxf(counts[g], 1.0f);
        c[k] = pooled[g * 128 + k] / cnt;
    }
    __syncthreads();

    if (tid < 192) {
        float acc = ub1[tid];
        for (int i = 0; i < 256; i++) acc += c[i] * uW1[i * 192 + tid];
        acc = (acc - urm1[tid]) * rsqrtf(urv1[tid] + 1e-5f) * ug1[tid] + ube1[tid];
        d1[tid] = fmaxf(acc, 0.0f);
    }
    __syncthreads();

    if (tid < 128) {
        float acc = ub2[tid];
        for (int i = 0; i < 192; i++) acc += d1[i] * uW2[i * 128 + tid];
        acc = (acc - urm2[tid]) * rsqrtf(urv2[tid] + 1e-5f) * ug2[tid] + ube2[tid];
        d2[tid] = fmaxf(acc, 0.0f);
    }
    __syncthreads();

    if (tid == 0) {
        float s = ub3[0];
        for (int i = 0; i < 128; i++) s += d2[i] * uW3[i];
        out[g] = 1.0f / (1.0f + expf(-s));
    }
}

extern "C" void kernel_launch(void* const* d_in, const int* in_sizes, int n_in,
                              void* d_out, int out_size, void* d_ws, size_t ws_size,
                              hipStream_t stream) {
    const float* x    = (const float*)d_in[0];
    const float* feat = (const float*)d_in[1];
    const float* W1   = (const float*)d_in[2];
    const float* b1   = (const float*)d_in[3];
    const float* W2   = (const float*)d_in[4];
    const float* b2   = (const float*)d_in[5];
    const float* fW1  = (const float*)d_in[6];
    const float* fb1  = (const float*)d_in[7];
    const float* fg1  = (const float*)d_in[8];
    const float* fbe1 = (const float*)d_in[9];
    const float* frm1 = (const float*)d_in[10];
    const float* frv1 = (const float*)d_in[11];
    const float* fW2  = (const float*)d_in[12];
    const float* fb2  = (const float*)d_in[13];
    const float* uW1  = (const float*)d_in[14];
    const float* ub1  = (const float*)d_in[15];
    const float* ug1  = (const float*)d_in[16];
    const float* ube1 = (const float*)d_in[17];
    const float* urm1 = (const float*)d_in[18];
    const float* urv1 = (const float*)d_in[19];
    const float* uW2  = (const float*)d_in[20];
    const float* ub2  = (const float*)d_in[21];
    const float* ug2  = (const float*)d_in[22];
    const float* ube2 = (const float*)d_in[23];
    const float* urm2 = (const float*)d_in[24];
    const float* urv2 = (const float*)d_in[25];
    const float* uW3  = (const float*)d_in[26];
    const float* ub3  = (const float*)d_in[27];
    const int* ei    = (const int*)d_in[28];   // [2, E]
    const int* batch = (const int*)d_in[29];   // [N]
    float* out = (float*)d_out;

    // workspace layout — total ~43 MB
    char* p = (char*)d_ws;
    float*  dis    = (float*)p;  p += (size_t)NN * 4;
    float2* xs     = (float2*)p; p += (size_t)NN * 8;          // x * dis (pre-scaled)
    bf16*   h1s    = (bf16*)p;   p += (size_t)NN * 64 * 2;     // relu(h1) * dis (pre-scaled)
    float*  counts = (float*)p;  p += (size_t)NG * 4;
    float*  pooled = (float*)p;  p += (size_t)NG * 128 * 4;
    int*    cnt    = (int*)p;    p += (size_t)NN * 4;          // in-degree / bucket cursor
    int*    bkt    = (int*)p;    p += (size_t)NN * KB * 4;     // src ids bucketed by dst
    int*    novf   = (int*)p;    p += 4;
    int*    ovf    = (int*)p;    p += (size_t)OVFCAP * 4;
    short*  w2t    = (short*)p;  p += (size_t)64 * 128 * 2;    // bf16 W2, transposed [col][k]

    hipMemsetAsync(cnt,    0, (size_t)NN * 4, stream);
    hipMemsetAsync(novf,   0, 4, stream);
    hipMemsetAsync(pooled, 0, (size_t)NG * 128 * 4, stream);

    k_bucket<<<(NE + 255) / 256, 256, 0, stream>>>(ei, cnt, bkt, ovf, novf);
    k_misc<<<32, 256, 0, stream>>>(batch, counts, W2, w2t);
    k_pre<<<(NN + 255) / 256, 256, 0, stream>>>(cnt, x, dis, xs);

    // GCN layer 1: fused parallel-gather + W1 + bias + relu (wave per node)
    k_h1g<<<(NN * 64 + 255) / 256, 256, 0, stream>>>(cnt, bkt, dis, xs, W1, b1,
                                                     novf, ovf, ei, h1s);

    // GCN layer 2: FUSED gather + MFMA + pool (block per 16-node tile)
    k_l2<<<NN / 16, 512, 0, stream>>>(cnt, bkt, dis, h1s, novf, ovf, ei,
                                      w2t, b2, batch, pooled);

    // fused MLP head
    k_head<<<NG, 256, 0, stream>>>(feat, fW1, fb1, fg1, fbe1, frm1, frv1, fW2, fb2,
                                   uW1, ub1, ug1, ube1, urm1, urv1,
                                   uW2, ub2, ug2, ube2, urm2, urv2, uW3, ub3,
                                   pooled, counts, out);
}

// Round 14
// 152.127 us; speedup vs baseline: 1.7334x; 1.1661x over previous
//
#include <hip/hip_runtime.h>
#include <hip/hip_bf16.h>
#include <math.h>

typedef __hip_bfloat16 bf16;
static __device__ __forceinline__ float b2f(bf16 v) { return __bfloat162float(v); }

typedef __bf16 bfx8 __attribute__((ext_vector_type(8)));
typedef float  fx4  __attribute__((ext_vector_type(4)));

constexpr int NN = 200000;   // nodes
constexpr int NE = 600000;   // edges
constexpr int NG = 512;      // graphs
constexpr int KB = 16;       // bucket capacity (Poisson(3): P(deg>16) tiny; overflow path kept)
constexpr int OVFCAP = 8192;

static __device__ __forceinline__ int clampi(int s) {
    return ((unsigned)s < (unsigned)NN) ? s : 0;   // safe addr for speculative loads
}

// ---------------- bucket edges by dst (also produces in-degree in cnt) ----------------
__global__ void k_bucket(const int* __restrict__ ei, int* __restrict__ cnt,
                         int* __restrict__ bkt, int* __restrict__ ovf, int* __restrict__ novf) {
    int e = blockIdx.x * blockDim.x + threadIdx.x;
    if (e >= NE) return;
    int s = ei[e], d = ei[NE + e];
    int slot = atomicAdd(&cnt[d], 1);
    if (slot < KB) bkt[d * KB + slot] = s;
    else { int o = atomicAdd(novf, 1); if (o < OVFCAP) ovf[o] = e; }
}

// ---------------- misc: counts[g] by binary search  +  W2 -> bf16 transposed ----------------
__global__ void k_misc(const int* __restrict__ batch, float* __restrict__ counts,
                       const float* __restrict__ W2, short* __restrict__ w2t) {
    int t = blockIdx.x * blockDim.x + threadIdx.x;
    if (t < 64 * 128) {                  // W2 [64][128] fp32 -> w2t [128 cols][64 k] bf16
        int k = t >> 7, c = t & 127;
        bf16 v = __float2bfloat16(W2[t]);
        w2t[c * 64 + k] = *(const short*)&v;
    }
    if (t < NG) {
        int g = t;
        int lo = 0, hi = NN;
        while (lo < hi) { int m = (lo + hi) >> 1; if (batch[m] < g) lo = m + 1; else hi = m; }
        int first = lo;
        lo = 0; hi = NN;
        while (lo < hi) { int m = (lo + hi) >> 1; if (batch[m] < g + 1) lo = m + 1; else hi = m; }
        counts[g] = (float)(lo - first);
    }
}

// ---------------- dis = rsqrt(deg+1); xs = x * dis (pre-scaled gather operand) ----------------
__global__ void k_pre(const int* __restrict__ cnt, const float* __restrict__ x,
                      float* __restrict__ dis, float2* __restrict__ xs) {
    int n = blockIdx.x * blockDim.x + threadIdx.x;
    if (n >= NN) return;
    float v = rsqrtf((float)cnt[n] + 1.0f);
    dis[n] = v;
    float2 xv = ((const float2*)x)[n];
    xs[n] = make_float2(xv.x * v, xv.y * v);
}

// ---------------- fused GCN layer 1: 4 nodes/wave, 16 lanes per node ----------------
// All 64 lanes carry an edge load (was: 16 of 64). 4-step shfl group-reduce.
// Each lane then computes 4 channels: h1s[d] = relu(dis[d]*(sum xs[s] + xs[d]) @ W1 + b1)*dis[d]
__global__ __launch_bounds__(256) void k_h1g(const int* __restrict__ cnt,
                      const int* __restrict__ bkt, const float* __restrict__ dis,
                      const float2* __restrict__ xs, const float* __restrict__ W1,
                      const float* __restrict__ b1,
                      const int* __restrict__ novf, const int* __restrict__ ovf,
                      const int* __restrict__ ei, bf16* __restrict__ h1s) {
    int wave = (blockIdx.x * 256 + threadIdx.x) >> 6;   // global wave id
    int lane = threadIdx.x & 63;
    int grp = lane >> 4, l16 = lane & 15;
    int d = wave * 4 + grp;                              // NN%4==0: always in range
    if (d >= NN) return;

    // speculative: bkt + xs race ahead of cnt
    int s = clampi(bkt[d * KB + l16]);
    int deg = cnt[d];
    float2 ps = xs[s];
    int degc = deg < KB ? deg : KB;
    float p0 = (l16 < degc) ? ps.x : 0.0f;
    float p1 = (l16 < degc) ? ps.y : 0.0f;

    if (deg > KB) {                          // rare overflow: group scans tiny ovf list
        int nov = *novf; if (nov > OVFCAP) nov = OVFCAP;
        for (int o = l16; o < nov; o += 16) {
            int e = ovf[o];
            if (ei[NE + e] == d) {
                float2 x2 = xs[ei[e]];
                p0 += x2.x; p1 += x2.y;
            }
        }
    }
#pragma unroll
    for (int m = 1; m < 16; m <<= 1) {       // reduce within 16-lane group
        p0 += __shfl_xor(p0, m, 64);
        p1 += __shfl_xor(p1, m, 64);
    }

    float wd = dis[d];
    float2 xd = xs[d];
    float a0 = (p0 + xd.x) * wd;
    float a1 = (p1 + xd.y) * wd;

    int c0 = l16 * 4;                        // my 4 channels
    float4 w0 = *(const float4*)&W1[c0];
    float4 w1 = *(const float4*)&W1[64 + c0];
    float4 bb = *(const float4*)&b1[c0];
    float r0 = fmaxf(a0 * w0.x + a1 * w1.x + bb.x, 0.0f) * wd;
    float r1 = fmaxf(a0 * w0.y + a1 * w1.y + bb.y, 0.0f) * wd;
    float r2 = fmaxf(a0 * w0.z + a1 * w1.z + bb.z, 0.0f) * wd;
    float r3 = fmaxf(a0 * w0.w + a1 * w1.w + bb.w, 0.0f) * wd;
    bf16 q0 = __float2bfloat16(r0), q1 = __float2bfloat16(r1);
    bf16 q2 = __float2bfloat16(r2), q3 = __float2bfloat16(r3);
    short4 pack = make_short4(*(const short*)&q0, *(const short*)&q1,
                              *(const short*)&q2, *(const short*)&q3);
    *(short4*)&((short*)h1s)[(size_t)d * 64 + c0] = pack;
}

// ---------------- rare tail (deg>8 / overflow): h1s rows pre-scaled, no dis loads --------
static __device__ __forceinline__ float agg_tail8(int d, int lane, int degc, int deg, float acc,
        const int* __restrict__ bkt, const bf16* __restrict__ h1s,
        const int* __restrict__ novf, const int* __restrict__ ovf, const int* __restrict__ ei) {
    for (int i = 8; i < degc; i += 4) {
        int4 sv = *(const int4*)&bkt[d * KB + i];
        int s0 = clampi(sv.x), s1 = clampi(sv.y), s2 = clampi(sv.z), s3 = clampi(sv.w);
        float v0 = b2f(h1s[(size_t)s0 * 64 + lane]);
        float v1 = b2f(h1s[(size_t)s1 * 64 + lane]);
        float v2 = b2f(h1s[(size_t)s2 * 64 + lane]);
        float v3 = b2f(h1s[(size_t)s3 * 64 + lane]);
        acc += v0;
        if (i + 1 < degc) acc += v1;
        if (i + 2 < degc) acc += v2;
        if (i + 3 < degc) acc += v3;
    }
    if (deg > KB) {
        int nov = *novf; if (nov > OVFCAP) nov = OVFCAP;
        for (int o = 0; o < nov; o++) {
            int e = ovf[o];
            if (ei[NE + e] == d) acc += b2f(h1s[(size_t)ei[e] * 64 + lane]);
        }
    }
    return acc;
}

// ---------------- per-node gather (lane = channel); flat to 8 edges, tail beyond ----------
static __device__ __forceinline__ float gather16(int d, int lane, int deg,
        const int* __restrict__ bkt, const bf16* __restrict__ h1s,
        const int* __restrict__ novf, const int* __restrict__ ovf, const int* __restrict__ ei) {
    float acc = b2f(h1s[(size_t)d * 64 + lane]);         // self term (pre-scaled)
    int4 sv = *(const int4*)&bkt[d * KB];                // speculative
    int s0 = clampi(sv.x), s1 = clampi(sv.y), s2 = clampi(sv.z), s3 = clampi(sv.w);
    float v0 = b2f(h1s[(size_t)s0 * 64 + lane]);
    float v1 = b2f(h1s[(size_t)s1 * 64 + lane]);
    float v2 = b2f(h1s[(size_t)s2 * 64 + lane]);
    float v3 = b2f(h1s[(size_t)s3 * 64 + lane]);
    acc += (deg > 0) ? v0 : 0.0f;
    acc += (deg > 1) ? v1 : 0.0f;
    acc += (deg > 2) ? v2 : 0.0f;
    acc += (deg > 3) ? v3 : 0.0f;
    if (deg > 4) {                                       // wave-uniform branch
        int4 t = *(const int4*)&bkt[d * KB + 4];
        int b0 = clampi(t.x), b1_ = clampi(t.y), b2_ = clampi(t.z), b3 = clampi(t.w);
        float w0 = b2f(h1s[(size_t)b0 * 64 + lane]);
        float w1 = b2f(h1s[(size_t)b1_ * 64 + lane]);
        float w2 = b2f(h1s[(size_t)b2_ * 64 + lane]);
        float w3 = b2f(h1s[(size_t)b3 * 64 + lane]);
        acc += w0;
        acc += (deg > 5) ? w1 : 0.0f;
        acc += (deg > 6) ? w2 : 0.0f;
        acc += (deg > 7) ? w3 : 0.0f;
    }
    if (deg > 8) acc = agg_tail8(d, lane, deg < KB ? deg : KB, deg, acc, bkt, h1s, novf, ovf, ei);
    return acc;
}

// ---------------- FUSED layer 2: 4 nodes/WAVE gather -> LDS -> MFMA -> pooled epilogue ------
// block = 256 thr = 4 waves = 16-node tile. Round-13 lever: 2x in-flight loads per wave
// (~20-28 outstanding) to hide L2/L3 gather latency. Phase 2: wave does col-tiles {wid, wid+4}.
__global__ __launch_bounds__(256) void k_l2(const int* __restrict__ cnt,
                        const int* __restrict__ bkt, const float* __restrict__ dis,
                        const bf16* __restrict__ h1s,
                        const int* __restrict__ novf, const int* __restrict__ ovf,
                        const int* __restrict__ ei,
                        const short* __restrict__ w2t, const float* __restrict__ b2v,
                        const int* __restrict__ batch, float* __restrict__ pooled) {
    __shared__ short asub[16 * 72];          // bf16 bits, row stride 72 (16B-aligned rows)
    int tid = threadIdx.x;
    int lane = tid & 63;
    int wid = tid >> 6;                      // 0..3
    int n0 = blockIdx.x * 16;
    int dbase = n0 + wid * 4;

    // ---- phase 1: gather 4 nodes; all loads independent, compiler interleaves ----
    int deg0 = cnt[dbase + 0], deg1 = cnt[dbase + 1];
    int deg2 = cnt[dbase + 2], deg3 = cnt[dbase + 3];
    float acc0 = gather16(dbase + 0, lane, deg0, bkt, h1s, novf, ovf, ei);
    float acc1 = gather16(dbase + 1, lane, deg1, bkt, h1s, novf, ovf, ei);
    float acc2 = gather16(dbase + 2, lane, deg2, bkt, h1s, novf, ovf, ei);
    float acc3 = gather16(dbase + 3, lane, deg3, bkt, h1s, novf, ovf, ei);
    float dd0 = dis[dbase + 0], dd1 = dis[dbase + 1];
    float dd2 = dis[dbase + 2], dd3 = dis[dbase + 3];

    bf16 r0 = __float2bfloat16(acc0 * dd0);
    bf16 r1 = __float2bfloat16(acc1 * dd1);
    bf16 r2 = __float2bfloat16(acc2 * dd2);
    bf16 r3 = __float2bfloat16(acc3 * dd3);
    asub[(wid * 4 + 0) * 72 + lane] = *(const short*)&r0;
    asub[(wid * 4 + 1) * 72 + lane] = *(const short*)&r1;
    asub[(wid * 4 + 2) * 72 + lane] = *(const short*)&r2;
    asub[(wid * 4 + 3) * 72 + lane] = *(const short*)&r3;
    __syncthreads();

    // ---- phase 2: col-tiles wid and wid+4 ----
    int lr = lane & 15, lq = lane >> 4;
    bfx8 af0 = *(const bfx8*)&asub[lr * 72 + lq * 8];
    bfx8 af1 = *(const bfx8*)&asub[lr * 72 + 32 + lq * 8];

    int rr0 = n0 + lq * 4;
    int g0 = batch[rr0 + 0], g1 = batch[rr0 + 1];
    int g2 = batch[rr0 + 2], g3 = batch[rr0 + 3];
    bool uni = (batch[n0] == batch[n0 + 15]);

#pragma unroll
    for (int t = 0; t < 2; t++) {
        int c = (wid + t * 4) * 16 + lr;
        const short* bcol = w2t + c * 64 + lq * 8;
        bfx8 bf0 = *(const bfx8*)(bcol);
        bfx8 bf1 = *(const bfx8*)(bcol + 32);
        fx4 acc = {0.0f, 0.0f, 0.0f, 0.0f};
        acc = __builtin_amdgcn_mfma_f32_16x16x32_bf16(af0, bf0, acc, 0, 0, 0);
        acc = __builtin_amdgcn_mfma_f32_16x16x32_bf16(af1, bf1, acc, 0, 0, 0);
        float bias = b2v[c];
        float v0 = fmaxf(acc[0] + bias, 0.0f);
        float v1 = fmaxf(acc[1] + bias, 0.0f);
        float v2 = fmaxf(acc[2] + bias, 0.0f);
        float v3 = fmaxf(acc[3] + bias, 0.0f);
        if (uni) {
            float s = (v0 + v1) + (v2 + v3);
            s += __shfl_xor(s, 16, 64);
            s += __shfl_xor(s, 32, 64);
            if (lq == 0) atomicAdd(&pooled[g0 * 128 + c], s);
        } else {
            float s = v0; int cg = g0;
            if (g1 == cg) s += v1; else { atomicAdd(&pooled[cg * 128 + c], s); s = v1; cg = g1; }
            if (g2 == cg) s += v2; else { atomicAdd(&pooled[cg * 128 + c], s); s = v2; cg = g2; }
            if (g3 == cg) s += v3; else { atomicAdd(&pooled[cg * 128 + c], s); s = v3; cg = g3; }
            atomicAdd(&pooled[cg * 128 + c], s);
        }
    }
}

// ---------------- fused head: feat MLP + fusion MLP + sigmoid, block per graph ----------------
__global__ void k_head(const float* __restrict__ feat,
                       const float* __restrict__ fW1, const float* __restrict__ fb1,
                       const float* __restrict__ fg1, const float* __restrict__ fbe1,
                       const float* __restrict__ frm1, const float* __restrict__ frv1,
                       const float* __restrict__ fW2, const float* __restrict__ fb2,
                       const float* __restrict__ uW1, const float* __restrict__ ub1,
                       const float* __restrict__ ug1, const float* __restrict__ ube1,
                       const float* __restrict__ urm1, const float* __restrict__ urv1,
                       const float* __restrict__ uW2, const float* __restrict__ ub2,
                       const float* __restrict__ ug2, const float* __restrict__ ube2,
                       const float* __restrict__ urm2, const float* __restrict__ urv2,
                       const float* __restrict__ uW3, const float* __restrict__ ub3,
                       const float* __restrict__ pooled, const float* __restrict__ counts,
                       float* __restrict__ out) {
    int g = blockIdx.x;
    int tid = threadIdx.x;
    __shared__ float t1[256], c[256], d1[192], d2[128];

    float f[8];
#pragma unroll
    for (int i = 0; i < 8; i++) f[i] = feat[g * 8 + i];

    {
        int j = tid;
        float acc = fb1[j];
#pragma unroll
        for (int i = 0; i < 8; i++) acc += f[i] * fW1[i * 256 + j];
        acc = (acc - frm1[j]) * rsqrtf(frv1[j] + 1e-5f) * fg1[j] + fbe1[j];
        t1[j] = fmaxf(acc, 0.0f);
    }
    __syncthreads();

    if (tid < 128) {
        float acc = fb2[tid];
        for (int j = 0; j < 256; j++) acc += t1[j] * fW2[j * 128 + tid];
        c[128 + tid] = acc;
    } else {
        int k = tid - 128;
        float cnt = fmaxf(counts[g], 1.0f);
        c[k] = pooled[g * 128 + k] / cnt;
    }
    __syncthreads();

    if (tid < 192) {
        float acc = ub1[tid];
        for (int i = 0; i < 256; i++) acc += c[i] * uW1[i * 192 + tid];
        acc = (acc - urm1[tid]) * rsqrtf(urv1[tid] + 1e-5f) * ug1[tid] + ube1[tid];
        d1[tid] = fmaxf(acc, 0.0f);
    }
    __syncthreads();

    if (tid < 128) {
        float acc = ub2[tid];
        for (int i = 0; i < 192; i++) acc += d1[i] * uW2[i * 128 + tid];
        acc = (acc - urm2[tid]) * rsqrtf(urv2[tid] + 1e-5f) * ug2[tid] + ube2[tid];
        d2[tid] = fmaxf(acc, 0.0f);
    }
    __syncthreads();

    if (tid == 0) {
        float s = ub3[0];
        for (int i = 0; i < 128; i++) s += d2[i] * uW3[i];
        out[g] = 1.0f / (1.0f + expf(-s));
    }
}

extern "C" void kernel_launch(void* const* d_in, const int* in_sizes, int n_in,
                              void* d_out, int out_size, void* d_ws, size_t ws_size,
                              hipStream_t stream) {
    const float* x    = (const float*)d_in[0];
    const float* feat = (const float*)d_in[1];
    const float* W1   = (const float*)d_in[2];
    const float* b1   = (const float*)d_in[3];
    const float* W2   = (const float*)d_in[4];
    const float* b2   = (const float*)d_in[5];
    const float* fW1  = (const float*)d_in[6];
    const float* fb1  = (const float*)d_in[7];
    const float* fg1  = (const float*)d_in[8];
    const float* fbe1 = (const float*)d_in[9];
    const float* frm1 = (const float*)d_in[10];
    const float* frv1 = (const float*)d_in[11];
    const float* fW2  = (const float*)d_in[12];
    const float* fb2  = (const float*)d_in[13];
    const float* uW1  = (const float*)d_in[14];
    const float* ub1  = (const float*)d_in[15];
    const float* ug1  = (const float*)d_in[16];
    const float* ube1 = (const float*)d_in[17];
    const float* urm1 = (const float*)d_in[18];
    const float* urv1 = (const float*)d_in[19];
    const float* uW2  = (const float*)d_in[20];
    const float* ub2  = (const float*)d_in[21];
    const float* ug2  = (const float*)d_in[22];
    const float* ube2 = (const float*)d_in[23];
    const float* urm2 = (const float*)d_in[24];
    const float* urv2 = (const float*)d_in[25];
    const float* uW3  = (const float*)d_in[26];
    const float* ub3  = (const float*)d_in[27];
    const int* ei    = (const int*)d_in[28];   // [2, E]
    const int* batch = (const int*)d_in[29];   // [N]
    float* out = (float*)d_out;

    // workspace layout — total ~43 MB
    char* p = (char*)d_ws;
    float*  dis    = (float*)p;  p += (size_t)NN * 4;
    float2* xs     = (float2*)p; p += (size_t)NN * 8;          // x * dis (pre-scaled)
    bf16*   h1s    = (bf16*)p;   p += (size_t)NN * 64 * 2;     // relu(h1) * dis (pre-scaled)
    float*  counts = (float*)p;  p += (size_t)NG * 4;
    float*  pooled = (float*)p;  p += (size_t)NG * 128 * 4;
    int*    cnt    = (int*)p;    p += (size_t)NN * 4;          // in-degree / bucket cursor
    int*    bkt    = (int*)p;    p += (size_t)NN * KB * 4;     // src ids bucketed by dst
    int*    novf   = (int*)p;    p += 4;
    int*    ovf    = (int*)p;    p += (size_t)OVFCAP * 4;
    short*  w2t    = (short*)p;  p += (size_t)64 * 128 * 2;    // bf16 W2, transposed [col][k]

    hipMemsetAsync(cnt,    0, (size_t)NN * 4, stream);
    hipMemsetAsync(novf,   0, 4, stream);
    hipMemsetAsync(pooled, 0, (size_t)NG * 128 * 4, stream);

    k_bucket<<<(NE + 255) / 256, 256, 0, stream>>>(ei, cnt, bkt, ovf, novf);
    k_misc<<<32, 256, 0, stream>>>(batch, counts, W2, w2t);
    k_pre<<<(NN + 255) / 256, 256, 0, stream>>>(cnt, x, dis, xs);

    // GCN layer 1: 4 nodes/wave, 16-lane groups (all lanes load edges in parallel)
    k_h1g<<<NN / 16, 256, 0, stream>>>(cnt, bkt, dis, xs, W1, b1, novf, ovf, ei, h1s);

    // GCN layer 2: FUSED gather (4 nodes/wave) + MFMA + pool (block per 16-node tile)
    k_l2<<<NN / 16, 256, 0, stream>>>(cnt, bkt, dis, h1s, novf, ovf, ei,
                                      w2t, b2, batch, pooled);

    // fused MLP head
    k_head<<<NG, 256, 0, stream>>>(feat, fW1, fb1, fg1, fbe1, frm1, frv1, fW2, fb2,
                                   uW1, ub1, ug1, ube1, urm1, urv1,
                                   uW2, ub2, ug2, ube2, urm2, urv2, uW3, ub3,
                                   pooled, counts, out);
}

// Round 15
// 149.306 us; speedup vs baseline: 1.7661x; 1.0189x over previous
//
#include <hip/hip_runtime.h>
#include <hip/hip_bf16.h>
#include <math.h>

typedef __hip_bfloat16 bf16;
static __device__ __forceinline__ float b2f(bf16 v) { return __bfloat162float(v); }

typedef __bf16 bfx8 __attribute__((ext_vector_type(8)));
typedef float  fx4  __attribute__((ext_vector_type(4)));

constexpr int NN = 200000;   // nodes
constexpr int NE = 600000;   // edges
constexpr int NG = 512;      // graphs
constexpr int KB = 16;       // bucket capacity (Poisson(3): P(deg>16) tiny; overflow path kept)
constexpr int OVFCAP = 8192;

static __device__ __forceinline__ int clampi(int s) {
    return ((unsigned)s < (unsigned)NN) ? s : 0;   // safe addr for speculative loads
}

// ---------------- bucket edges by dst + fused misc (counts, W2->bf16T, zero pooled) --------
__global__ void k_bucket(const int* __restrict__ ei, int* __restrict__ cnt,
                         int* __restrict__ bkt, int* __restrict__ ovf, int* __restrict__ novf,
                         const int* __restrict__ batch, float* __restrict__ counts,
                         const float* __restrict__ W2, short* __restrict__ w2t,
                         float* __restrict__ pooled) {
    int t = blockIdx.x * blockDim.x + threadIdx.x;
    if (t < NG * 128) pooled[t] = 0.0f;          // zero pooled (k_l2 atomics target)
    if (t < 64 * 128) {                          // W2 [64][128] fp32 -> w2t [128][64] bf16
        int k = t >> 7, c = t & 127;
        bf16 v = __float2bfloat16(W2[t]);
        w2t[c * 64 + k] = *(const short*)&v;
    }
    if (t < NG) {                                // counts[g] via binary search (batch sorted)
        int g = t;
        int lo = 0, hi = NN;
        while (lo < hi) { int m = (lo + hi) >> 1; if (batch[m] < g) lo = m + 1; else hi = m; }
        int first = lo;
        lo = 0; hi = NN;
        while (lo < hi) { int m = (lo + hi) >> 1; if (batch[m] < g + 1) lo = m + 1; else hi = m; }
        counts[g] = (float)(lo - first);
    }
    if (t >= NE) return;
    int s = ei[t], d = ei[NE + t];
    int slot = atomicAdd(&cnt[d], 1);
    if (slot < KB) bkt[d * KB + slot] = s;
    else { int o = atomicAdd(novf, 1); if (o < OVFCAP) ovf[o] = t; }
}

// ---------------- dis = rsqrt(deg+1); xs = x * dis (pre-scaled gather operand) ----------------
__global__ void k_pre(const int* __restrict__ cnt, const float* __restrict__ x,
                      float* __restrict__ dis, float2* __restrict__ xs) {
    int n = blockIdx.x * blockDim.x + threadIdx.x;
    if (n >= NN) return;
    float v = rsqrtf((float)cnt[n] + 1.0f);
    dis[n] = v;
    float2 xv = ((const float2*)x)[n];
    xs[n] = make_float2(xv.x * v, xv.y * v);
}

// ---------------- fused GCN layer 1: 4 nodes/wave, 16 lanes per node ----------------
__global__ __launch_bounds__(256) void k_h1g(const int* __restrict__ cnt,
                      const int* __restrict__ bkt, const float* __restrict__ dis,
                      const float2* __restrict__ xs, const float* __restrict__ W1,
                      const float* __restrict__ b1,
                      const int* __restrict__ novf, const int* __restrict__ ovf,
                      const int* __restrict__ ei, bf16* __restrict__ h1s) {
    int wave = (blockIdx.x * 256 + threadIdx.x) >> 6;   // global wave id
    int lane = threadIdx.x & 63;
    int grp = lane >> 4, l16 = lane & 15;
    int d = wave * 4 + grp;
    if (d >= NN) return;

    int s = clampi(bkt[d * KB + l16]);       // speculative: races ahead of cnt
    int deg = cnt[d];
    float2 ps = xs[s];
    int degc = deg < KB ? deg : KB;
    float p0 = (l16 < degc) ? ps.x : 0.0f;
    float p1 = (l16 < degc) ? ps.y : 0.0f;

    if (deg > KB) {                          // rare overflow
        int nov = *novf; if (nov > OVFCAP) nov = OVFCAP;
        for (int o = l16; o < nov; o += 16) {
            int e = ovf[o];
            if (ei[NE + e] == d) {
                float2 x2 = xs[ei[e]];
                p0 += x2.x; p1 += x2.y;
            }
        }
    }
#pragma unroll
    for (int m = 1; m < 16; m <<= 1) {
        p0 += __shfl_xor(p0, m, 64);
        p1 += __shfl_xor(p1, m, 64);
    }

    float wd = dis[d];
    float2 xd = xs[d];
    float a0 = (p0 + xd.x) * wd;
    float a1 = (p1 + xd.y) * wd;

    int c0 = l16 * 4;
    float4 w0 = *(const float4*)&W1[c0];
    float4 w1 = *(const float4*)&W1[64 + c0];
    float4 bb = *(const float4*)&b1[c0];
    float r0 = fmaxf(a0 * w0.x + a1 * w1.x + bb.x, 0.0f) * wd;
    float r1 = fmaxf(a0 * w0.y + a1 * w1.y + bb.y, 0.0f) * wd;
    float r2 = fmaxf(a0 * w0.z + a1 * w1.z + bb.z, 0.0f) * wd;
    float r3 = fmaxf(a0 * w0.w + a1 * w1.w + bb.w, 0.0f) * wd;
    bf16 q0 = __float2bfloat16(r0), q1 = __float2bfloat16(r1);
    bf16 q2 = __float2bfloat16(r2), q3 = __float2bfloat16(r3);
    short4 pack = make_short4(*(const short*)&q0, *(const short*)&q1,
                              *(const short*)&q2, *(const short*)&q3);
    *(short4*)&((short*)h1s)[(size_t)d * 64 + c0] = pack;
}

// ---------------- rare tail (deg>8 / overflow) ----------------
static __device__ __forceinline__ float agg_tail8(int d, int lane, int degc, int deg, float acc,
        const int* __restrict__ bkt, const bf16* __restrict__ h1s,
        const int* __restrict__ novf, const int* __restrict__ ovf, const int* __restrict__ ei) {
    for (int i = 8; i < degc; i += 4) {
        int4 sv = *(const int4*)&bkt[d * KB + i];
        int s0 = clampi(sv.x), s1 = clampi(sv.y), s2 = clampi(sv.z), s3 = clampi(sv.w);
        float v0 = b2f(h1s[(size_t)s0 * 64 + lane]);
        float v1 = b2f(h1s[(size_t)s1 * 64 + lane]);
        float v2 = b2f(h1s[(size_t)s2 * 64 + lane]);
        float v3 = b2f(h1s[(size_t)s3 * 64 + lane]);
        acc += v0;
        if (i + 1 < degc) acc += v1;
        if (i + 2 < degc) acc += v2;
        if (i + 3 < degc) acc += v3;
    }
    if (deg > KB) {
        int nov = *novf; if (nov > OVFCAP) nov = OVFCAP;
        for (int o = 0; o < nov; o++) {
            int e = ovf[o];
            if (ei[NE + e] == d) acc += b2f(h1s[(size_t)ei[e] * 64 + lane]);
        }
    }
    return acc;
}

// ---------------- per-node gather (lane = channel); flat to 8 edges, tail beyond ----------
static __device__ __forceinline__ float gather16(int d, int lane, int deg,
        const int* __restrict__ bkt, const bf16* __restrict__ h1s,
        const int* __restrict__ novf, const int* __restrict__ ovf, const int* __restrict__ ei) {
    float acc = b2f(h1s[(size_t)d * 64 + lane]);         // self term (pre-scaled)
    int4 sv = *(const int4*)&bkt[d * KB];                // speculative
    int s0 = clampi(sv.x), s1 = clampi(sv.y), s2 = clampi(sv.z), s3 = clampi(sv.w);
    float v0 = b2f(h1s[(size_t)s0 * 64 + lane]);
    float v1 = b2f(h1s[(size_t)s1 * 64 + lane]);
    float v2 = b2f(h1s[(size_t)s2 * 64 + lane]);
    float v3 = b2f(h1s[(size_t)s3 * 64 + lane]);
    acc += (deg > 0) ? v0 : 0.0f;
    acc += (deg > 1) ? v1 : 0.0f;
    acc += (deg > 2) ? v2 : 0.0f;
    acc += (deg > 3) ? v3 : 0.0f;
    if (deg > 4) {                                       // wave-uniform branch
        int4 t = *(const int4*)&bkt[d * KB + 4];
        int b0 = clampi(t.x), b1_ = clampi(t.y), b2_ = clampi(t.z), b3 = clampi(t.w);
        float w0 = b2f(h1s[(size_t)b0 * 64 + lane]);
        float w1 = b2f(h1s[(size_t)b1_ * 64 + lane]);
        float w2 = b2f(h1s[(size_t)b2_ * 64 + lane]);
        float w3 = b2f(h1s[(size_t)b3 * 64 + lane]);
        acc += w0;
        acc += (deg > 5) ? w1 : 0.0f;
        acc += (deg > 6) ? w2 : 0.0f;
        acc += (deg > 7) ? w3 : 0.0f;
    }
    if (deg > 8) acc = agg_tail8(d, lane, deg < KB ? deg : KB, deg, acc, bkt, h1s, novf, ovf, ei);
    return acc;
}

// ---------------- WAVE-INDEPENDENT layer 2: each wave owns a full 16-node tile -------------
// No __syncthreads anywhere: gather 16 rows (lane=channel) -> own LDS slice ->
// s_waitcnt lgkmcnt(0) (wave-local transpose) -> ds_read_b128 A-frags -> 16 MFMAs -> pool.
// Round-15 rationale: round-14 showed per-wave ILP saturated; the barrier duty-cycle and
// occupancy cap were the residual. 4 independent waves/block, own LDS slices.
__global__ __launch_bounds__(256) void k_l2(const int* __restrict__ cnt,
                        const int* __restrict__ bkt, const float* __restrict__ dis,
                        const bf16* __restrict__ h1s,
                        const int* __restrict__ novf, const int* __restrict__ ovf,
                        const int* __restrict__ ei,
                        const short* __restrict__ w2t, const float* __restrict__ b2v,
                        const int* __restrict__ batch, float* __restrict__ pooled) {
    __shared__ short asub[4][16 * 72];       // per-wave slice, row stride 72
    int tid = threadIdx.x;
    int lane = tid & 63;
    int wid = tid >> 6;                      // 0..3, fully independent waves
    int n0 = blockIdx.x * 64 + wid * 16;     // this wave's 16 nodes
    short* slice = asub[wid];

    // ---- gather 16 nodes; unroll-4 pipelines 4 nodes' loads at a time ----
#pragma unroll 4
    for (int n = 0; n < 16; n++) {
        int d = n0 + n;
        int deg = cnt[d];
        float a = gather16(d, lane, deg, bkt, h1s, novf, ovf, ei);
        bf16 r = __float2bfloat16(a * dis[d]);
        slice[n * 72 + lane] = *(const short*)&r;
    }
    // wave-local LDS transpose: order ds_writes before ds_reads (no __syncthreads needed)
    asm volatile("s_waitcnt lgkmcnt(0)" ::: "memory");
    __builtin_amdgcn_sched_barrier(0);

    // ---- A-fragments, then 8 col-tiles x 2 MFMA ----
    int lr = lane & 15, lq = lane >> 4;
    bfx8 af0 = *(const bfx8*)&slice[lr * 72 + lq * 8];
    bfx8 af1 = *(const bfx8*)&slice[lr * 72 + 32 + lq * 8];

    int rr0 = n0 + lq * 4;
    int g0 = batch[rr0 + 0], g1 = batch[rr0 + 1];
    int g2 = batch[rr0 + 2], g3 = batch[rr0 + 3];
    bool uni = (batch[n0] == batch[n0 + 15]);

#pragma unroll
    for (int t = 0; t < 8; t++) {
        int c = t * 16 + lr;
        const short* bcol = w2t + c * 64 + lq * 8;
        bfx8 bf0 = *(const bfx8*)(bcol);
        bfx8 bf1 = *(const bfx8*)(bcol + 32);
        fx4 acc = {0.0f, 0.0f, 0.0f, 0.0f};
        acc = __builtin_amdgcn_mfma_f32_16x16x32_bf16(af0, bf0, acc, 0, 0, 0);
        acc = __builtin_amdgcn_mfma_f32_16x16x32_bf16(af1, bf1, acc, 0, 0, 0);
        float bias = b2v[c];
        float v0 = fmaxf(acc[0] + bias, 0.0f);
        float v1 = fmaxf(acc[1] + bias, 0.0f);
        float v2 = fmaxf(acc[2] + bias, 0.0f);
        float v3 = fmaxf(acc[3] + bias, 0.0f);
        if (uni) {
            float s = (v0 + v1) + (v2 + v3);
            s += __shfl_xor(s, 16, 64);
            s += __shfl_xor(s, 32, 64);
            if (lq == 0) atomicAdd(&pooled[g0 * 128 + c], s);
        } else {
            float s = v0; int cg = g0;
            if (g1 == cg) s += v1; else { atomicAdd(&pooled[cg * 128 + c], s); s = v1; cg = g1; }
            if (g2 == cg) s += v2; else { atomicAdd(&pooled[cg * 128 + c], s); s = v2; cg = g2; }
            if (g3 == cg) s += v3; else { atomicAdd(&pooled[cg * 128 + c], s); s = v3; cg = g3; }
            atomicAdd(&pooled[cg * 128 + c], s);
        }
    }
}

// ---------------- fused head: feat MLP + fusion MLP + sigmoid, block per graph ----------------
__global__ void k_head(const float* __restrict__ feat,
                       const float* __restrict__ fW1, const float* __restrict__ fb1,
                       const float* __restrict__ fg1, const float* __restrict__ fbe1,
                       const float* __restrict__ frm1, const float* __restrict__ frv1,
                       const float* __restrict__ fW2, const float* __restrict__ fb2,
                       const float* __restrict__ uW1, const float* __restrict__ ub1,
                       const float* __restrict__ ug1, const float* __restrict__ ube1,
                       const float* __restrict__ urm1, const float* __restrict__ urv1,
                       const float* __restrict__ uW2, const float* __restrict__ ub2,
                       const float* __restrict__ ug2, const float* __restrict__ ube2,
                       const float* __restrict__ urm2, const float* __restrict__ urv2,
                       const float* __restrict__ uW3, const float* __restrict__ ub3,
                       const float* __restrict__ pooled, const float* __restrict__ counts,
                       float* __restrict__ out) {
    int g = blockIdx.x;
    int tid = threadIdx.x;
    __shared__ float t1[256], c[256], d1[192], d2[128];

    float f[8];
#pragma unroll
    for (int i = 0; i < 8; i++) f[i] = feat[g * 8 + i];

    {
        int j = tid;
        float acc = fb1[j];
#pragma unroll
        for (int i = 0; i < 8; i++) acc += f[i] * fW1[i * 256 + j];
        acc = (acc - frm1[j]) * rsqrtf(frv1[j] + 1e-5f) * fg1[j] + fbe1[j];
        t1[j] = fmaxf(acc, 0.0f);
    }
    __syncthreads();

    if (tid < 128) {
        float acc = fb2[tid];
        for (int j = 0; j < 256; j++) acc += t1[j] * fW2[j * 128 + tid];
        c[128 + tid] = acc;
    } else {
        int k = tid - 128;
        float cnt = fmaxf(counts[g], 1.0f);
        c[k] = pooled[g * 128 + k] / cnt;
    }
    __syncthreads();

    if (tid < 192) {
        float acc = ub1[tid];
        for (int i = 0; i < 256; i++) acc += c[i] * uW1[i * 192 + tid];
        acc = (acc - urm1[tid]) * rsqrtf(urv1[tid] + 1e-5f) * ug1[tid] + ube1[tid];
        d1[tid] = fmaxf(acc, 0.0f);
    }
    __syncthreads();

    if (tid < 128) {
        float acc = ub2[tid];
        for (int i = 0; i < 192; i++) acc += d1[i] * uW2[i * 128 + tid];
        acc = (acc - urm2[tid]) * rsqrtf(urv2[tid] + 1e-5f) * ug2[tid] + ube2[tid];
        d2[tid] = fmaxf(acc, 0.0f);
    }
    __syncthreads();

    if (tid == 0) {
        float s = ub3[0];
        for (int i = 0; i < 128; i++) s += d2[i] * uW3[i];
        out[g] = 1.0f / (1.0f + expf(-s));
    }
}

extern "C" void kernel_launch(void* const* d_in, const int* in_sizes, int n_in,
                              void* d_out, int out_size, void* d_ws, size_t ws_size,
                              hipStream_t stream) {
    const float* x    = (const float*)d_in[0];
    const float* feat = (const float*)d_in[1];
    const float* W1   = (const float*)d_in[2];
    const float* b1   = (const float*)d_in[3];
    const float* W2   = (const float*)d_in[4];
    const float* b2   = (const float*)d_in[5];
    const float* fW1  = (const float*)d_in[6];
    const float* fb1  = (const float*)d_in[7];
    const float* fg1  = (const float*)d_in[8];
    const float* fbe1 = (const float*)d_in[9];
    const float* frm1 = (const float*)d_in[10];
    const float* frv1 = (const float*)d_in[11];
    const float* fW2  = (const float*)d_in[12];
    const float* fb2  = (const float*)d_in[13];
    const float* uW1  = (const float*)d_in[14];
    const float* ub1  = (const float*)d_in[15];
    const float* ug1  = (const float*)d_in[16];
    const float* ube1 = (const float*)d_in[17];
    const float* urm1 = (const float*)d_in[18];
    const float* urv1 = (const float*)d_in[19];
    const float* uW2  = (const float*)d_in[20];
    const float* ub2  = (const float*)d_in[21];
    const float* ug2  = (const float*)d_in[22];
    const float* ube2 = (const float*)d_in[23];
    const float* urm2 = (const float*)d_in[24];
    const float* urv2 = (const float*)d_in[25];
    const float* uW3  = (const float*)d_in[26];
    const float* ub3  = (const float*)d_in[27];
    const int* ei    = (const int*)d_in[28];   // [2, E]
    const int* batch = (const int*)d_in[29];   // [N]
    float* out = (float*)d_out;

    // workspace layout — total ~43 MB (cnt & novf adjacent: single memset)
    char* p = (char*)d_ws;
    float*  dis    = (float*)p;  p += (size_t)NN * 4;
    float2* xs     = (float2*)p; p += (size_t)NN * 8;          // x * dis (pre-scaled)
    bf16*   h1s    = (bf16*)p;   p += (size_t)NN * 64 * 2;     // relu(h1) * dis (pre-scaled)
    float*  counts = (float*)p;  p += (size_t)NG * 4;
    float*  pooled = (float*)p;  p += (size_t)NG * 128 * 4;
    int*    cnt    = (int*)p;    p += (size_t)NN * 4;          // in-degree / bucket cursor
    int*    novf   = (int*)p;    p += 4;                       // adjacent to cnt
    int*    ovf    = (int*)p;    p += (size_t)OVFCAP * 4;
    int*    bkt    = (int*)p;    p += (size_t)NN * KB * 4;     // src ids bucketed by dst
    short*  w2t    = (short*)p;  p += (size_t)64 * 128 * 2;    // bf16 W2, transposed [col][k]

    hipMemsetAsync(cnt, 0, (size_t)NN * 4 + 4, stream);        // cnt + novf in one shot

    // bucket + (counts, W2->bf16T, zero pooled) fused
    k_bucket<<<(NE + 255) / 256, 256, 0, stream>>>(ei, cnt, bkt, ovf, novf,
                                                   batch, counts, W2, w2t, pooled);
    k_pre<<<(NN + 255) / 256, 256, 0, stream>>>(cnt, x, dis, xs);

    // GCN layer 1: 4 nodes/wave, 16-lane groups
    k_h1g<<<NN / 16, 256, 0, stream>>>(cnt, bkt, dis, xs, W1, b1, novf, ovf, ei, h1s);

    // GCN layer 2: wave-independent gather+MFMA+pool (wave per 16-node tile, no barriers)
    k_l2<<<NN / 64, 256, 0, stream>>>(cnt, bkt, dis, h1s, novf, ovf, ei,
                                      w2t, b2, batch, pooled);

    // fused MLP head
    k_head<<<NG, 256, 0, stream>>>(feat, fW1, fb1, fg1, fbe1, frm1, frv1, fW2, fb2,
                                   uW1, ub1, ug1, ube1, urm1, urv1,
                                   uW2, ub2, ug2, ube2, urm2, urv2, uW3, ub3,
                                   pooled, counts, out);
}

// Round 16
// 140.074 us; speedup vs baseline: 1.8825x; 1.0659x over previous
//
#include <hip/hip_runtime.h>
#include <hip/hip_bf16.h>
#include <math.h>

typedef __hip_bfloat16 bf16;
static __device__ __forceinline__ float b2f(bf16 v) { return __bfloat162float(v); }

typedef __bf16 bfx8 __attribute__((ext_vector_type(8)));
typedef float  fx4  __attribute__((ext_vector_type(4)));

constexpr int NN = 200000;   // nodes
constexpr int NE = 600000;   // edges
constexpr int NG = 512;      // graphs
constexpr int KB = 16;       // bucket capacity (Poisson(3): P(deg>16) tiny; overflow path kept)
constexpr int OVFCAP = 8192;

static __device__ __forceinline__ int clampi(int s) {
    return ((unsigned)s < (unsigned)NN) ? s : 0;   // safe addr for speculative loads
}

// ---------------- bucket edges by dst + fused misc (counts, W2->bf16T, zero pooled) --------
__global__ void k_bucket(const int* __restrict__ ei, int* __restrict__ cnt,
                         int* __restrict__ bkt, int* __restrict__ ovf, int* __restrict__ novf,
                         const int* __restrict__ batch, float* __restrict__ counts,
                         const float* __restrict__ W2, short* __restrict__ w2t,
                         float* __restrict__ pooled) {
    int t = blockIdx.x * blockDim.x + threadIdx.x;
    if (t < NG * 128) pooled[t] = 0.0f;          // zero pooled (k_l2 atomics target)
    if (t < 64 * 128) {                          // W2 [64][128] fp32 -> w2t [128][64] bf16
        int k = t >> 7, c = t & 127;
        bf16 v = __float2bfloat16(W2[t]);
        w2t[c * 64 + k] = *(const short*)&v;
    }
    if (t < NG) {                                // counts[g] via binary search (batch sorted)
        int g = t;
        int lo = 0, hi = NN;
        while (lo < hi) { int m = (lo + hi) >> 1; if (batch[m] < g) lo = m + 1; else hi = m; }
        int first = lo;
        lo = 0; hi = NN;
        while (lo < hi) { int m = (lo + hi) >> 1; if (batch[m] < g + 1) lo = m + 1; else hi = m; }
        counts[g] = (float)(lo - first);
    }
    if (t >= NE) return;
    int s = ei[t], d = ei[NE + t];
    int slot = atomicAdd(&cnt[d], 1);
    if (slot < KB) bkt[d * KB + slot] = s;
    else { int o = atomicAdd(novf, 1); if (o < OVFCAP) ovf[o] = t; }
}

// ---------------- dis = rsqrt(deg+1); xs = x * dis (pre-scaled gather operand) ----------------
__global__ void k_pre(const int* __restrict__ cnt, const float* __restrict__ x,
                      float* __restrict__ dis, float2* __restrict__ xs) {
    int n = blockIdx.x * blockDim.x + threadIdx.x;
    if (n >= NN) return;
    float v = rsqrtf((float)cnt[n] + 1.0f);
    dis[n] = v;
    float2 xv = ((const float2*)x)[n];
    xs[n] = make_float2(xv.x * v, xv.y * v);
}

// ---------------- fused GCN layer 1: 4 nodes/wave, 16 lanes per node ----------------
__global__ __launch_bounds__(256) void k_h1g(const int* __restrict__ cnt,
                      const int* __restrict__ bkt, const float* __restrict__ dis,
                      const float2* __restrict__ xs, const float* __restrict__ W1,
                      const float* __restrict__ b1,
                      const int* __restrict__ novf, const int* __restrict__ ovf,
                      const int* __restrict__ ei, bf16* __restrict__ h1s) {
    int wave = (blockIdx.x * 256 + threadIdx.x) >> 6;   // global wave id
    int lane = threadIdx.x & 63;
    int grp = lane >> 4, l16 = lane & 15;
    int d = wave * 4 + grp;
    if (d >= NN) return;

    int s = clampi(bkt[d * KB + l16]);       // speculative: races ahead of cnt
    int deg = cnt[d];
    float2 ps = xs[s];
    int degc = deg < KB ? deg : KB;
    float p0 = (l16 < degc) ? ps.x : 0.0f;
    float p1 = (l16 < degc) ? ps.y : 0.0f;

    if (deg > KB) {                          // rare overflow
        int nov = *novf; if (nov > OVFCAP) nov = OVFCAP;
        for (int o = l16; o < nov; o += 16) {
            int e = ovf[o];
            if (ei[NE + e] == d) {
                float2 x2 = xs[ei[e]];
                p0 += x2.x; p1 += x2.y;
            }
        }
    }
#pragma unroll
    for (int m = 1; m < 16; m <<= 1) {
        p0 += __shfl_xor(p0, m, 64);
        p1 += __shfl_xor(p1, m, 64);
    }

    float wd = dis[d];
    float2 xd = xs[d];
    float a0 = (p0 + xd.x) * wd;
    float a1 = (p1 + xd.y) * wd;

    int c0 = l16 * 4;
    float4 w0 = *(const float4*)&W1[c0];
    float4 w1 = *(const float4*)&W1[64 + c0];
    float4 bb = *(const float4*)&b1[c0];
    float r0 = fmaxf(a0 * w0.x + a1 * w1.x + bb.x, 0.0f) * wd;
    float r1 = fmaxf(a0 * w0.y + a1 * w1.y + bb.y, 0.0f) * wd;
    float r2 = fmaxf(a0 * w0.z + a1 * w1.z + bb.z, 0.0f) * wd;
    float r3 = fmaxf(a0 * w0.w + a1 * w1.w + bb.w, 0.0f) * wd;
    bf16 q0 = __float2bfloat16(r0), q1 = __float2bfloat16(r1);
    bf16 q2 = __float2bfloat16(r2), q3 = __float2bfloat16(r3);
    short4 pack = make_short4(*(const short*)&q0, *(const short*)&q1,
                              *(const short*)&q2, *(const short*)&q3);
    *(short4*)&((short*)h1s)[(size_t)d * 64 + c0] = pack;
}

// ---------------- rare tail (deg>8 / overflow) ----------------
static __device__ __forceinline__ float agg_tail8(int d, int lane, int degc, int deg, float acc,
        const int* __restrict__ bkt, const bf16* __restrict__ h1s,
        const int* __restrict__ novf, const int* __restrict__ ovf, const int* __restrict__ ei) {
    for (int i = 8; i < degc; i += 4) {
        int4 sv = *(const int4*)&bkt[d * KB + i];
        int s0 = clampi(sv.x), s1 = clampi(sv.y), s2 = clampi(sv.z), s3 = clampi(sv.w);
        float v0 = b2f(h1s[(size_t)s0 * 64 + lane]);
        float v1 = b2f(h1s[(size_t)s1 * 64 + lane]);
        float v2 = b2f(h1s[(size_t)s2 * 64 + lane]);
        float v3 = b2f(h1s[(size_t)s3 * 64 + lane]);
        acc += v0;
        if (i + 1 < degc) acc += v1;
        if (i + 2 < degc) acc += v2;
        if (i + 3 < degc) acc += v3;
    }
    if (deg > KB) {
        int nov = *novf; if (nov > OVFCAP) nov = OVFCAP;
        for (int o = 0; o < nov; o++) {
            int e = ovf[o];
            if (ei[NE + e] == d) acc += b2f(h1s[(size_t)ei[e] * 64 + lane]);
        }
    }
    return acc;
}

// ---------------- per-node gather (lane = channel); flat to 8 edges, tail beyond ----------
static __device__ __forceinline__ float gather16(int d, int lane, int deg,
        const int* __restrict__ bkt, const bf16* __restrict__ h1s,
        const int* __restrict__ novf, const int* __restrict__ ovf, const int* __restrict__ ei) {
    float acc = b2f(h1s[(size_t)d * 64 + lane]);         // self term (pre-scaled)
    int4 sv = *(const int4*)&bkt[d * KB];                // speculative
    int s0 = clampi(sv.x), s1 = clampi(sv.y), s2 = clampi(sv.z), s3 = clampi(sv.w);
    float v0 = b2f(h1s[(size_t)s0 * 64 + lane]);
    float v1 = b2f(h1s[(size_t)s1 * 64 + lane]);
    float v2 = b2f(h1s[(size_t)s2 * 64 + lane]);
    float v3 = b2f(h1s[(size_t)s3 * 64 + lane]);
    acc += (deg > 0) ? v0 : 0.0f;
    acc += (deg > 1) ? v1 : 0.0f;
    acc += (deg > 2) ? v2 : 0.0f;
    acc += (deg > 3) ? v3 : 0.0f;
    if (deg > 4) {                                       // wave-uniform branch
        int4 t = *(const int4*)&bkt[d * KB + 4];
        int b0 = clampi(t.x), b1_ = clampi(t.y), b2_ = clampi(t.z), b3 = clampi(t.w);
        float w0 = b2f(h1s[(size_t)b0 * 64 + lane]);
        float w1 = b2f(h1s[(size_t)b1_ * 64 + lane]);
        float w2 = b2f(h1s[(size_t)b2_ * 64 + lane]);
        float w3 = b2f(h1s[(size_t)b3 * 64 + lane]);
        acc += w0;
        acc += (deg > 5) ? w1 : 0.0f;
        acc += (deg > 6) ? w2 : 0.0f;
        acc += (deg > 7) ? w3 : 0.0f;
    }
    if (deg > 8) acc = agg_tail8(d, lane, deg < KB ? deg : KB, deg, acc, bkt, h1s, novf, ovf, ei);
    return acc;
}

// ---------------- MFMA + pooled epilogue for one 16-node tile (wave does col-tiles wid,wid+4)
static __device__ __forceinline__ void mfma_pool(int n0, int lane, int wid,
        bfx8 af0, bfx8 af1,
        const short* __restrict__ w2t, const float* __restrict__ b2v,
        const int* __restrict__ batch, float* __restrict__ pooled) {
    int lr = lane & 15, lq = lane >> 4;
    int rr0 = n0 + lq * 4;
    int g0 = batch[rr0 + 0], g1 = batch[rr0 + 1];
    int g2 = batch[rr0 + 2], g3 = batch[rr0 + 3];
    bool uni = (batch[n0] == batch[n0 + 15]);

#pragma unroll
    for (int t = 0; t < 2; t++) {
        int c = (wid + t * 4) * 16 + lr;
        const short* bcol = w2t + c * 64 + lq * 8;
        bfx8 bf0 = *(const bfx8*)(bcol);
        bfx8 bf1 = *(const bfx8*)(bcol + 32);
        fx4 acc = {0.0f, 0.0f, 0.0f, 0.0f};
        acc = __builtin_amdgcn_mfma_f32_16x16x32_bf16(af0, bf0, acc, 0, 0, 0);
        acc = __builtin_amdgcn_mfma_f32_16x16x32_bf16(af1, bf1, acc, 0, 0, 0);
        float bias = b2v[c];
        float v0 = fmaxf(acc[0] + bias, 0.0f);
        float v1 = fmaxf(acc[1] + bias, 0.0f);
        float v2 = fmaxf(acc[2] + bias, 0.0f);
        float v3 = fmaxf(acc[3] + bias, 0.0f);
        if (uni) {
            float s = (v0 + v1) + (v2 + v3);
            s += __shfl_xor(s, 16, 64);
            s += __shfl_xor(s, 32, 64);
            if (lq == 0) atomicAdd(&pooled[g0 * 128 + c], s);
        } else {
            float s = v0; int cg = g0;
            if (g1 == cg) s += v1; else { atomicAdd(&pooled[cg * 128 + c], s); s = v1; cg = g1; }
            if (g2 == cg) s += v2; else { atomicAdd(&pooled[cg * 128 + c], s); s = v2; cg = g2; }
            if (g3 == cg) s += v3; else { atomicAdd(&pooled[cg * 128 + c], s); s = v3; cg = g3; }
            atomicAdd(&pooled[cg * 128 + c], s);
        }
    }
}

// ---------------- FUSED layer 2, 2-tile software pipeline -----------------------------------
// Round-14 structure (4 waves x 4 nodes, barrier) restored; on top: block owns TWO 16-node
// tiles. After tile-A barrier each wave reads its A-frags, ISSUES tile-B's gather loads,
// then runs A's MFMA+pool while B's loads fly (scheduler interleaves independent work).
__global__ __launch_bounds__(256) void k_l2(const int* __restrict__ cnt,
                        const int* __restrict__ bkt, const float* __restrict__ dis,
                        const bf16* __restrict__ h1s,
                        const int* __restrict__ novf, const int* __restrict__ ovf,
                        const int* __restrict__ ei,
                        const short* __restrict__ w2t, const float* __restrict__ b2v,
                        const int* __restrict__ batch, float* __restrict__ pooled) {
    __shared__ short asub[2][16 * 72];       // one buffer per tile, row stride 72
    int tid = threadIdx.x;
    int lane = tid & 63;
    int wid = tid >> 6;                      // 0..3
    int n0A = blockIdx.x * 32;
    int n0B = n0A + 16;
    int dA = n0A + wid * 4;
    int dB = n0B + wid * 4;

    // ---- gather tile A (4 nodes/wave) ----
    float aA0 = gather16(dA + 0, lane, cnt[dA + 0], bkt, h1s, novf, ovf, ei);
    float aA1 = gather16(dA + 1, lane, cnt[dA + 1], bkt, h1s, novf, ovf, ei);
    float aA2 = gather16(dA + 2, lane, cnt[dA + 2], bkt, h1s, novf, ovf, ei);
    float aA3 = gather16(dA + 3, lane, cnt[dA + 3], bkt, h1s, novf, ovf, ei);
    {
        bf16 r0 = __float2bfloat16(aA0 * dis[dA + 0]);
        bf16 r1 = __float2bfloat16(aA1 * dis[dA + 1]);
        bf16 r2 = __float2bfloat16(aA2 * dis[dA + 2]);
        bf16 r3 = __float2bfloat16(aA3 * dis[dA + 3]);
        asub[0][(wid * 4 + 0) * 72 + lane] = *(const short*)&r0;
        asub[0][(wid * 4 + 1) * 72 + lane] = *(const short*)&r1;
        asub[0][(wid * 4 + 2) * 72 + lane] = *(const short*)&r2;
        asub[0][(wid * 4 + 3) * 72 + lane] = *(const short*)&r3;
    }
    __syncthreads();

    int lr = lane & 15, lq = lane >> 4;
    bfx8 afA0 = *(const bfx8*)&asub[0][lr * 72 + lq * 8];
    bfx8 afA1 = *(const bfx8*)&asub[0][lr * 72 + 32 + lq * 8];

    // ---- issue tile-B gather (independent: overlaps with tile-A MFMA below) ----
    float aB0 = gather16(dB + 0, lane, cnt[dB + 0], bkt, h1s, novf, ovf, ei);
    float aB1 = gather16(dB + 1, lane, cnt[dB + 1], bkt, h1s, novf, ovf, ei);
    float aB2 = gather16(dB + 2, lane, cnt[dB + 2], bkt, h1s, novf, ovf, ei);
    float aB3 = gather16(dB + 3, lane, cnt[dB + 3], bkt, h1s, novf, ovf, ei);

    // ---- MFMA + pool tile A (fills B's load latency) ----
    mfma_pool(n0A, lane, wid, afA0, afA1, w2t, b2v, batch, pooled);

    // ---- write tile B, barrier, MFMA + pool tile B ----
    {
        bf16 r0 = __float2bfloat16(aB0 * dis[dB + 0]);
        bf16 r1 = __float2bfloat16(aB1 * dis[dB + 1]);
        bf16 r2 = __float2bfloat16(aB2 * dis[dB + 2]);
        bf16 r3 = __float2bfloat16(aB3 * dis[dB + 3]);
        asub[1][(wid * 4 + 0) * 72 + lane] = *(const short*)&r0;
        asub[1][(wid * 4 + 1) * 72 + lane] = *(const short*)&r1;
        asub[1][(wid * 4 + 2) * 72 + lane] = *(const short*)&r2;
        asub[1][(wid * 4 + 3) * 72 + lane] = *(const short*)&r3;
    }
    __syncthreads();
    bfx8 afB0 = *(const bfx8*)&asub[1][lr * 72 + lq * 8];
    bfx8 afB1 = *(const bfx8*)&asub[1][lr * 72 + 32 + lq * 8];
    mfma_pool(n0B, lane, wid, afB0, afB1, w2t, b2v, batch, pooled);
}

// ---------------- fused head: feat MLP + fusion MLP + sigmoid, block per graph ----------------
__global__ void k_head(const float* __restrict__ feat,
                       const float* __restrict__ fW1, const float* __restrict__ fb1,
                       const float* __restrict__ fg1, const float* __restrict__ fbe1,
                       const float* __restrict__ frm1, const float* __restrict__ frv1,
                       const float* __restrict__ fW2, const float* __restrict__ fb2,
                       const float* __restrict__ uW1, const float* __restrict__ ub1,
                       const float* __restrict__ ug1, const float* __restrict__ ube1,
                       const float* __restrict__ urm1, const float* __restrict__ urv1,
                       const float* __restrict__ uW2, const float* __restrict__ ub2,
                       const float* __restrict__ ug2, const float* __restrict__ ube2,
                       const float* __restrict__ urm2, const float* __restrict__ urv2,
                       const float* __restrict__ uW3, const float* __restrict__ ub3,
                       const float* __restrict__ pooled, const float* __restrict__ counts,
                       float* __restrict__ out) {
    int g = blockIdx.x;
    int tid = threadIdx.x;
    __shared__ float t1[256], c[256], d1[192], d2[128];

    float f[8];
#pragma unroll
    for (int i = 0; i < 8; i++) f[i] = feat[g * 8 + i];

    {
        int j = tid;
        float acc = fb1[j];
#pragma unroll
        for (int i = 0; i < 8; i++) acc += f[i] * fW1[i * 256 + j];
        acc = (acc - frm1[j]) * rsqrtf(frv1[j] + 1e-5f) * fg1[j] + fbe1[j];
        t1[j] = fmaxf(acc, 0.0f);
    }
    __syncthreads();

    if (tid < 128) {
        float acc = fb2[tid];
        for (int j = 0; j < 256; j++) acc += t1[j] * fW2[j * 128 + tid];
        c[128 + tid] = acc;
    } else {
        int k = tid - 128;
        float cnt = fmaxf(counts[g], 1.0f);
        c[k] = pooled[g * 128 + k] / cnt;
    }
    __syncthreads();

    if (tid < 192) {
        float acc = ub1[tid];
        for (int i = 0; i < 256; i++) acc += c[i] * uW1[i * 192 + tid];
        acc = (acc - urm1[tid]) * rsqrtf(urv1[tid] + 1e-5f) * ug1[tid] + ube1[tid];
        d1[tid] = fmaxf(acc, 0.0f);
    }
    __syncthreads();

    if (tid < 128) {
        float acc = ub2[tid];
        for (int i = 0; i < 192; i++) acc += d1[i] * uW2[i * 128 + tid];
        acc = (acc - urm2[tid]) * rsqrtf(urv2[tid] + 1e-5f) * ug2[tid] + ube2[tid];
        d2[tid] = fmaxf(acc, 0.0f);
    }
    __syncthreads();

    if (tid == 0) {
        float s = ub3[0];
        for (int i = 0; i < 128; i++) s += d2[i] * uW3[i];
        out[g] = 1.0f / (1.0f + expf(-s));
    }
}

extern "C" void kernel_launch(void* const* d_in, const int* in_sizes, int n_in,
                              void* d_out, int out_size, void* d_ws, size_t ws_size,
                              hipStream_t stream) {
    const float* x    = (const float*)d_in[0];
    const float* feat = (const float*)d_in[1];
    const float* W1   = (const float*)d_in[2];
    const float* b1   = (const float*)d_in[3];
    const float* W2   = (const float*)d_in[4];
    const float* b2   = (const float*)d_in[5];
    const float* fW1  = (const float*)d_in[6];
    const float* fb1  = (const float*)d_in[7];
    const float* fg1  = (const float*)d_in[8];
    const float* fbe1 = (const float*)d_in[9];
    const float* frm1 = (const float*)d_in[10];
    const float* frv1 = (const float*)d_in[11];
    const float* fW2  = (const float*)d_in[12];
    const float* fb2  = (const float*)d_in[13];
    const float* uW1  = (const float*)d_in[14];
    const float* ub1  = (const float*)d_in[15];
    const float* ug1  = (const float*)d_in[16];
    const float* ube1 = (const float*)d_in[17];
    const float* urm1 = (const float*)d_in[18];
    const float* urv1 = (const float*)d_in[19];
    const float* uW2  = (const float*)d_in[20];
    const float* ub2  = (const float*)d_in[21];
    const float* ug2  = (const float*)d_in[22];
    const float* ube2 = (const float*)d_in[23];
    const float* urm2 = (const float*)d_in[24];
    const float* urv2 = (const float*)d_in[25];
    const float* uW3  = (const float*)d_in[26];
    const float* ub3  = (const float*)d_in[27];
    const int* ei    = (const int*)d_in[28];   // [2, E]
    const int* batch = (const int*)d_in[29];   // [N]
    float* out = (float*)d_out;

    // workspace layout — total ~43 MB (cnt & novf adjacent: single memset)
    char* p = (char*)d_ws;
    float*  dis    = (float*)p;  p += (size_t)NN * 4;
    float2* xs     = (float2*)p; p += (size_t)NN * 8;          // x * dis (pre-scaled)
    bf16*   h1s    = (bf16*)p;   p += (size_t)NN * 64 * 2;     // relu(h1) * dis (pre-scaled)
    float*  counts = (float*)p;  p += (size_t)NG * 4;
    float*  pooled = (float*)p;  p += (size_t)NG * 128 * 4;
    int*    cnt    = (int*)p;    p += (size_t)NN * 4;          // in-degree / bucket cursor
    int*    novf   = (int*)p;    p += 4;                       // adjacent to cnt
    int*    ovf    = (int*)p;    p += (size_t)OVFCAP * 4;
    int*    bkt    = (int*)p;    p += (size_t)NN * KB * 4;     // src ids bucketed by dst
    short*  w2t    = (short*)p;  p += (size_t)64 * 128 * 2;    // bf16 W2, transposed [col][k]

    hipMemsetAsync(cnt, 0, (size_t)NN * 4 + 4, stream);        // cnt + novf in one shot

    // bucket + (counts, W2->bf16T, zero pooled) fused
    k_bucket<<<(NE + 255) / 256, 256, 0, stream>>>(ei, cnt, bkt, ovf, novf,
                                                   batch, counts, W2, w2t, pooled);
    k_pre<<<(NN + 255) / 256, 256, 0, stream>>>(cnt, x, dis, xs);

    // GCN layer 1: 4 nodes/wave, 16-lane groups
    k_h1g<<<NN / 16, 256, 0, stream>>>(cnt, bkt, dis, xs, W1, b1, novf, ovf, ei, h1s);

    // GCN layer 2: 2-tile pipelined gather+MFMA+pool (block per 32 nodes)
    k_l2<<<NN / 32, 256, 0, stream>>>(cnt, bkt, dis, h1s, novf, ovf, ei,
                                      w2t, b2, batch, pooled);

    // fused MLP head
    k_head<<<NG, 256, 0, stream>>>(feat, fW1, fb1, fg1, fbe1, frm1, frv1, fW2, fb2,
                                   uW1, ub1, ug1, ube1, urm1, urv1,
                                   uW2, ub2, ug2, ube2, urm2, urv2, uW3, ub3,
                                   pooled, counts, out);
}